// Round 1
// baseline (383.507 us; speedup 1.0000x reference)
//
#include <hip/hip_runtime.h>

#define NN 10000
#define BB 8
#define EE 160000
#define DH 128
#define LN_EPS 1e-5f

typedef unsigned short ushort_t;
typedef unsigned int uint_t;

typedef __bf16 bf16x8 __attribute__((ext_vector_type(8)));
typedef float floatx4 __attribute__((ext_vector_type(4)));

__device__ __forceinline__ float b2f(uint_t u) { return __uint_as_float(u << 16); }
__device__ __forceinline__ ushort_t f2b(float f) {
    uint_t u = __float_as_uint(f);
    return (ushort_t)((u + 0x7fffu + ((u >> 16) & 1u)) >> 16);
}
__device__ __forceinline__ uint_t pack2(float lo, float hi) {
    return (uint_t)f2b(lo) | ((uint_t)f2b(hi) << 16);
}
__device__ __forceinline__ float sigm(float x) { return 1.0f / (1.0f + __expf(-x)); }
__device__ __forceinline__ float tanh_fast(float x) {
    float ex = __expf(2.0f * x);
    return 1.0f - 2.0f / (ex + 1.0f);
}
// accumulate 8 bf16 (uint4) with weight w
__device__ __forceinline__ void acc8(float* a, float w, uint4 v) {
    a[0] += w * __uint_as_float(v.x << 16);
    a[1] += w * __uint_as_float(v.x & 0xffff0000u);
    a[2] += w * __uint_as_float(v.y << 16);
    a[3] += w * __uint_as_float(v.y & 0xffff0000u);
    a[4] += w * __uint_as_float(v.z << 16);
    a[5] += w * __uint_as_float(v.z & 0xffff0000u);
    a[6] += w * __uint_as_float(v.w << 16);
    a[7] += w * __uint_as_float(v.w & 0xffff0000u);
}

// ---------------- CSR build ----------------

__global__ void count_deg(const int* __restrict__ ei, int* __restrict__ cnt) {
    int e = blockIdx.x * 256 + threadIdx.x;
    if (e < EE) atomicAdd(&cnt[ei[EE + e]], 1);
}

__global__ __launch_bounds__(256) void scan1(const int* __restrict__ cnt,
                                             int* __restrict__ offs,
                                             int* __restrict__ bsum) {
    __shared__ int s[256];
    const int t = threadIdx.x, idx = blockIdx.x * 256 + t;
    int x = (idx < NN) ? cnt[idx] : 0;
    s[t] = x;
    __syncthreads();
    for (int o = 1; o < 256; o <<= 1) {
        int v = s[t];
        int u = (t >= o) ? s[t - o] : 0;
        __syncthreads();
        s[t] = v + u;
        __syncthreads();
    }
    if (idx < NN) offs[idx] = s[t] - x;  // block-local exclusive
    if (t == 255) bsum[blockIdx.x] = s[255];
}

__global__ __launch_bounds__(64) void scan2(int* __restrict__ bsum, int* __restrict__ offs) {
    __shared__ int sb[40];
    const int t = threadIdx.x;
    if (t < 40) sb[t] = bsum[t];
    __syncthreads();
    if (t == 0) {
        int acc = 0;
        for (int i = 0; i < 40; ++i) {
            int v = sb[i];
            sb[i] = acc;
            acc += v;
        }
        offs[NN] = EE;
    }
    __syncthreads();
    if (t < 40) bsum[t] = sb[t];
}

__global__ __launch_bounds__(256) void scan3(const int* __restrict__ cnt,
                                             const int* __restrict__ bsum,
                                             int* __restrict__ offs,
                                             int* __restrict__ cursor,
                                             float* __restrict__ dis) {
    const int idx = blockIdx.x * 256 + threadIdx.x;
    if (idx < NN) {
        int off = offs[idx] + bsum[blockIdx.x];
        offs[idx] = off;
        cursor[idx] = off;
        dis[idx] = rsqrtf((float)(cnt[idx] + 1));
    }
}

// csr: src index + bf16(dis[src]) weight
__global__ void fill_csr(const int* __restrict__ ei, int* __restrict__ cursor,
                         const float* __restrict__ dis, int* __restrict__ csr_src,
                         ushort_t* __restrict__ csr_w) {
    int e = blockIdx.x * 256 + threadIdx.x;
    if (e < EE) {
        int s = ei[e];
        int d = ei[EE + e];
        int pos = atomicAdd(&cursor[d], 1);
        csr_src[pos] = s;
        csr_w[pos] = f2b(dis[s]);
    }
}

// ---------------- pack x,h -> bf16 + weight transpose (merged) ----------------

__global__ __launch_bounds__(256) void packwt_k(const float* __restrict__ x,
                                                const float* __restrict__ h,
                                                ushort_t* __restrict__ xb,
                                                ushort_t* __restrict__ hb,
                                                const float* __restrict__ Wz,
                                                const float* __restrict__ Wr,
                                                const float* __restrict__ Wc,
                                                ushort_t* __restrict__ Wt_zr,
                                                ushort_t* __restrict__ Wt_c) {
    if (blockIdx.x < 10000) {
        const size_t o = ((size_t)blockIdx.x * 256 + threadIdx.x) * 4;
        float4 vx = *(const float4*)(x + o);
        uint2 px;
        px.x = pack2(vx.x, vx.y);
        px.y = pack2(vx.z, vx.w);
        *(uint2*)(xb + o) = px;
        float4 vh = *(const float4*)(h + o);
        uint2 ph;
        ph.x = pack2(vh.x, vh.y);
        ph.y = pack2(vh.z, vh.w);
        *(uint2*)(hb + o) = ph;
    } else {
        const int col = blockIdx.x - 10000, k = threadIdx.x;
        if (col < 256) {
            float v = (col < 128) ? Wz[(size_t)k * 128 + col]
                                  : Wr[(size_t)k * 128 + col - 128];
            Wt_zr[(size_t)col * 256 + k] = f2b(v);
        } else {
            int c2 = col - 256;
            Wt_c[(size_t)c2 * 256 + k] = f2b(Wc[(size_t)k * 128 + c2]);
        }
    }
}

// ---------------- gatherB: one wave per node, all 8 batches per wave ----------------
// dst[b,n] = dis[n] * ( sum_e dis[s]*src[b,s] + dis[n]*src[b,n] )
// The CSR (edges + weights) is SHARED across the batch: walk it once per node.
// Wave layout: 4 groups of 16 lanes; group g covers batches {g, g+4}; lane il
// owns cols il*8..il*8+7. Edge index/weight are wave-uniform -> v_readlane to
// SGPRs (scalar addressing, SGPR fmac operand). No cross-lane reduction needed.
// Edges are independent -> unroll 4 for ~16 loads in flight per wave.

template <int NB>
__global__ __launch_bounds__(256) void gatherB(
    const ushort_t* __restrict__ src0, const ushort_t* __restrict__ src1,
    const int* __restrict__ offs, const int* __restrict__ csr_src,
    const ushort_t* __restrict__ csr_w, const float* __restrict__ dis,
    ushort_t* __restrict__ dst0, ushort_t* __restrict__ dst1) {
    const int tid = threadIdx.x, lane = tid & 63;
    const int n = __builtin_amdgcn_readfirstlane((blockIdx.x << 2) + (tid >> 6));
    const int g = lane >> 4, il = lane & 15;
    // element offsets within a [B][N][128] buffer for batch g and g+4
    const uint_t lo0 = (uint_t)g * (NN * 128u) + (uint_t)il * 8u;
    const uint_t lo1 = lo0 + 4u * NN * 128u;

    float ax0[8], ax1[8], ah0[8], ah1[8];
#pragma unroll
    for (int j = 0; j < 8; ++j) {
        ax0[j] = 0.f;
        ax1[j] = 0.f;
        ah0[j] = 0.f;
        ah1[j] = 0.f;
    }

    const float dn = dis[n];
    {  // self row, weight dn inside the sum
        const ushort_t* r0 = src0 + (size_t)n * 128;
        acc8(ax0, dn, *(const uint4*)(r0 + lo0));
        acc8(ax1, dn, *(const uint4*)(r0 + lo1));
        if (NB == 2) {
            const ushort_t* r1 = src1 + (size_t)n * 128;
            acc8(ah0, dn, *(const uint4*)(r1 + lo0));
            acc8(ah1, dn, *(const uint4*)(r1 + lo1));
        }
    }

    const int e0 = offs[n], e1 = offs[n + 1];
    for (int ch = e0; ch < e1; ch += 64) {
        const int rem = e1 - ch;
        int idx = 0, wb = 0;
        if (lane < rem) {
            idx = csr_src[ch + lane];
            wb = (int)((uint_t)csr_w[ch + lane] << 16);
        }
        const int m = rem < 64 ? rem : 64;
#pragma unroll 4
        for (int i = 0; i < m; ++i) {
            const int s = __builtin_amdgcn_readlane(idx, i);
            const float w = __uint_as_float((uint_t)__builtin_amdgcn_readlane(wb, i));
            const ushort_t* r0 = src0 + (size_t)s * 128;
            acc8(ax0, w, *(const uint4*)(r0 + lo0));
            acc8(ax1, w, *(const uint4*)(r0 + lo1));
            if (NB == 2) {
                const ushort_t* r1 = src1 + (size_t)s * 128;
                acc8(ah0, w, *(const uint4*)(r1 + lo0));
                acc8(ah1, w, *(const uint4*)(r1 + lo1));
            }
        }
    }

    // scale by dis[n], pack, store: each lane owns (batch, col-chunk) exclusively
    const size_t ob0 = ((size_t)g * NN + n) * 128 + (size_t)il * 8;
    const size_t ob1 = ob0 + (size_t)4 * NN * 128;
    uint4 st;
    st.x = pack2(ax0[0] * dn, ax0[1] * dn);
    st.y = pack2(ax0[2] * dn, ax0[3] * dn);
    st.z = pack2(ax0[4] * dn, ax0[5] * dn);
    st.w = pack2(ax0[6] * dn, ax0[7] * dn);
    *(uint4*)(dst0 + ob0) = st;
    st.x = pack2(ax1[0] * dn, ax1[1] * dn);
    st.y = pack2(ax1[2] * dn, ax1[3] * dn);
    st.z = pack2(ax1[4] * dn, ax1[5] * dn);
    st.w = pack2(ax1[6] * dn, ax1[7] * dn);
    *(uint4*)(dst0 + ob1) = st;
    if (NB == 2) {
        st.x = pack2(ah0[0] * dn, ah0[1] * dn);
        st.y = pack2(ah0[2] * dn, ah0[3] * dn);
        st.z = pack2(ah0[4] * dn, ah0[5] * dn);
        st.w = pack2(ah0[6] * dn, ah0[7] * dn);
        *(uint4*)(dst1 + ob0) = st;
        st.x = pack2(ah1[0] * dn, ah1[1] * dn);
        st.y = pack2(ah1[2] * dn, ah1[3] * dn);
        st.z = pack2(ah1[4] * dn, ah1[5] * dn);
        st.w = pack2(ah1[6] * dn, ah1[7] * dn);
        *(uint4*)(dst1 + ob1) = st;
    }
}

// ---------------- GEMM 128x128 tile, K=256 = [A1 | A2] @ Wt, fused epilogues ------
// PHASE 0: mode=blockIdx.y (0: z=sigma->z_buf bf16; 1: r=sigma, rh=r*h->rh bf16)
// PHASE 1: mode 2: tanh, GRU blend, LayerNorm -> out f32

template <int PHASE>
__global__ __launch_bounds__(256) void gemm_k(
    const ushort_t* __restrict__ A1, const ushort_t* __restrict__ A2,
    const ushort_t* __restrict__ Wt, const float* __restrict__ bz,
    const float* __restrict__ br, const float* __restrict__ bc,
    const float* __restrict__ h_prev, const ushort_t* __restrict__ z_in,
    const float* __restrict__ gamma, const float* __restrict__ beta,
    ushort_t* __restrict__ z_out, ushort_t* __restrict__ rh_out,
    float* __restrict__ f_out) {
    __shared__ __align__(16) ushort_t As[128 * 72];
    __shared__ __align__(16) ushort_t Bs[128 * 72];
    const int tid = threadIdx.x;
    const int rb0 = blockIdx.x * 128;
    const int mode = (PHASE == 1) ? 2 : blockIdx.y;
    const int cb0 = (mode == 1) ? 128 : 0;

    const int wv = tid >> 6, lane = tid & 63;
    const int l15 = lane & 15, q = lane >> 4;
    const int sr = tid >> 1;
    const int kh = (tid & 1) * 32;

    floatx4 acc[2][8];
#pragma unroll
    for (int i = 0; i < 2; ++i)
#pragma unroll
        for (int j = 0; j < 8; ++j) acc[i][j] = (floatx4){0.f, 0.f, 0.f, 0.f};

    for (int k0 = 0; k0 < 256; k0 += 64) {
        {
            const int kg = k0 + kh;
            const ushort_t* s = (kg < 128) ? (A1 + (size_t)(rb0 + sr) * 128 + kg)
                                           : (A2 + (size_t)(rb0 + sr) * 128 + (kg - 128));
            ushort_t* dst = &As[sr * 72 + kh];
#pragma unroll
            for (int i = 0; i < 4; ++i) *(uint4*)(dst + i * 8) = *(const uint4*)(s + i * 8);
        }
        {
            const ushort_t* s = Wt + (size_t)(cb0 + sr) * 256 + k0 + kh;
            ushort_t* dst = &Bs[sr * 72 + kh];
#pragma unroll
            for (int i = 0; i < 4; ++i) *(uint4*)(dst + i * 8) = *(const uint4*)(s + i * 8);
        }
        __syncthreads();
#pragma unroll
        for (int ks = 0; ks < 2; ++ks) {
            const int ko = ks * 32 + q * 8;
            bf16x8 a0 = *(const bf16x8*)&As[(wv * 32 + l15) * 72 + ko];
            bf16x8 a1 = *(const bf16x8*)&As[(wv * 32 + 16 + l15) * 72 + ko];
#pragma unroll
            for (int j = 0; j < 8; ++j) {
                bf16x8 b = *(const bf16x8*)&Bs[(j * 16 + l15) * 72 + ko];
                acc[0][j] = __builtin_amdgcn_mfma_f32_16x16x32_bf16(a0, b, acc[0][j], 0, 0, 0);
                acc[1][j] = __builtin_amdgcn_mfma_f32_16x16x32_bf16(a1, b, acc[1][j], 0, 0, 0);
            }
        }
        __syncthreads();
    }

    // C/D: col = j*16 + l15, row = rb0 + wv*32 + i*16 + q*4 + v
    if (mode == 0) {
        float bv[8];
#pragma unroll
        for (int j = 0; j < 8; ++j) bv[j] = bz[j * 16 + l15];
#pragma unroll
        for (int i = 0; i < 2; ++i)
#pragma unroll
            for (int j = 0; j < 8; ++j)
#pragma unroll
                for (int v = 0; v < 4; ++v) {
                    int row = rb0 + wv * 32 + i * 16 + q * 4 + v;
                    z_out[(size_t)row * 128 + j * 16 + l15] = f2b(sigm(acc[i][j][v] + bv[j]));
                }
    } else if (mode == 1) {
        float bv[8];
#pragma unroll
        for (int j = 0; j < 8; ++j) bv[j] = br[j * 16 + l15];
#pragma unroll
        for (int i = 0; i < 2; ++i)
#pragma unroll
            for (int j = 0; j < 8; ++j)
#pragma unroll
                for (int v = 0; v < 4; ++v) {
                    int row = rb0 + wv * 32 + i * 16 + q * 4 + v;
                    float r = sigm(acc[i][j][v] + bv[j]);
                    float hh = h_prev[(size_t)row * 128 + j * 16 + l15];
                    rh_out[(size_t)row * 128 + j * 16 + l15] = f2b(r * hh);
                }
    } else {
        float bv[8], gv[8], bev[8];
#pragma unroll
        for (int j = 0; j < 8; ++j) {
            bv[j] = bc[j * 16 + l15];
            gv[j] = gamma[j * 16 + l15];
            bev[j] = beta[j * 16 + l15];
        }
#pragma unroll
        for (int i = 0; i < 2; ++i)
#pragma unroll
            for (int v = 0; v < 4; ++v) {
                const int row = rb0 + wv * 32 + i * 16 + q * 4 + v;
                float hn[8];
                float s = 0.f;
#pragma unroll
                for (int j = 0; j < 8; ++j) {
                    float hc = tanh_fast(acc[i][j][v] + bv[j]);
                    float zz = b2f((uint_t)z_in[(size_t)row * 128 + j * 16 + l15]);
                    float hh = h_prev[(size_t)row * 128 + j * 16 + l15];
                    hn[j] = (1.0f - zz) * hh + zz * hc;
                    s += hn[j];
                }
#pragma unroll
                for (int o = 8; o > 0; o >>= 1) s += __shfl_xor(s, o);  // 16-lane quad
                float mu = s * (1.0f / 128.0f);
                float vv = 0.f;
#pragma unroll
                for (int j = 0; j < 8; ++j) {
                    float d = hn[j] - mu;
                    vv += d * d;
                }
#pragma unroll
                for (int o = 8; o > 0; o >>= 1) vv += __shfl_xor(vv, o);
                float inv = rsqrtf(vv * (1.0f / 128.0f) + LN_EPS);
#pragma unroll
                for (int j = 0; j < 8; ++j)
                    f_out[(size_t)row * 128 + j * 16 + l15] =
                        (hn[j] - mu) * inv * gv[j] + bev[j];
            }
    }
}

// ---------------- launch ----------------

extern "C" void kernel_launch(void* const* d_in, const int* in_sizes, int n_in,
                              void* d_out, int out_size, void* d_ws, size_t ws_size,
                              hipStream_t stream) {
    const float* x = (const float*)d_in[0];
    const int* ei = (const int*)d_in[1];
    const float* h = (const float*)d_in[2];
    const float* Wz = (const float*)d_in[3];
    const float* bz = (const float*)d_in[4];
    const float* Wr = (const float*)d_in[5];
    const float* br = (const float*)d_in[6];
    const float* Wc = (const float*)d_in[7];
    const float* bcv = (const float*)d_in[8];
    const float* gamma = (const float*)d_in[9];
    const float* beta = (const float*)d_in[10];
    float* out = (float*)d_out;

    char* w = (char*)d_ws;
    int* offs = (int*)(w + 0);                    //    40,004 B
    float* dis = (float*)(w + 40960);             //    40,000 B
    int* csr_src = (int*)(w + 81920);             //   640,000 B
    ushort_t* csr_w = (ushort_t*)(w + 721920);    //   320,000 B
    ushort_t* Wt_zr = (ushort_t*)(w + 1041920);   //   131,072 B
    ushort_t* Wt_c = (ushort_t*)(w + 1172992);    //    65,536 B
    ushort_t* xb = (ushort_t*)(w + 1239040);      // 20,480,000 B
    ushort_t* hb = (ushort_t*)(w + 21719040);     // 20,480,000 B
    ushort_t* agg_x = (ushort_t*)(w + 42199040);  // 20,480,000 B
    ushort_t* agg_h = (ushort_t*)(w + 62679040);  // 20,480,000 B -> end 83,159,040
    // aliases (strict lifetime reuse on one stream):
    int* cnt = (int*)(w + 1239040);     // dead after fill_csr, before packwt_k
    int* cursor = (int*)(w + 1280000);  // dead after fill_csr
    int* bsum = (int*)(w + 1320000);    // dead after scan3
    ushort_t* z_buf = xb;      // xb dead after gatherB<2>; written by gemm<0>
    ushort_t* rh_bf = hb;      // hb dead after gatherB<2>; written by gemm<0>
    ushort_t* agg_rh = agg_h;  // agg_h dead after gemm<0>

    hipMemsetAsync(cnt, 0, NN * sizeof(int), stream);
    count_deg<<<EE / 256, 256, 0, stream>>>(ei, cnt);
    scan1<<<40, 256, 0, stream>>>(cnt, offs, bsum);
    scan2<<<1, 64, 0, stream>>>(bsum, offs);
    scan3<<<40, 256, 0, stream>>>(cnt, bsum, offs, cursor, dis);
    fill_csr<<<EE / 256, 256, 0, stream>>>(ei, cursor, dis, csr_src, csr_w);
    packwt_k<<<10384, 256, 0, stream>>>(x, h, xb, hb, Wz, Wr, Wc, Wt_zr, Wt_c);

    // agg_x, agg_h in one fused pass: one wave per node covers all 8 batches
    gatherB<2><<<NN / 4, 256, 0, stream>>>(xb, hb, offs, csr_src, csr_w, dis,
                                           agg_x, agg_h);
    // z (y=0) and rh (y=1) from one GEMM over [agg_x|agg_h]
    gemm_k<0><<<dim3(80000 / 128, 2), 256, 0, stream>>>(
        agg_x, agg_h, Wt_zr, bz, br, bcv, h, (const ushort_t*)0, gamma, beta,
        z_buf, rh_bf, (float*)0);
    gatherB<1><<<NN / 4, 256, 0, stream>>>(rh_bf, (const ushort_t*)0, offs,
                                           csr_src, csr_w, dis, agg_rh,
                                           (ushort_t*)0);
    // out = LN(GRU(tanh([agg_x|agg_rh]@Wc + bc)))
    gemm_k<1><<<dim3(80000 / 128, 1), 256, 0, stream>>>(
        agg_x, agg_rh, Wt_c, bz, br, bcv, h, z_buf, gamma, beta,
        (ushort_t*)0, (ushort_t*)0, out);
}

// Round 2
// 330.036 us; speedup vs baseline: 1.1620x; 1.1620x over previous
//
#include <hip/hip_runtime.h>

#define NN 10000
#define BB 8
#define EE 160000
#define DH 128
#define LN_EPS 1e-5f

typedef unsigned short ushort_t;
typedef unsigned int uint_t;

typedef __bf16 bf16x8 __attribute__((ext_vector_type(8)));
typedef float floatx4 __attribute__((ext_vector_type(4)));
typedef float floatx2 __attribute__((ext_vector_type(2)));

__device__ __forceinline__ float b2f(uint_t u) { return __uint_as_float(u << 16); }
__device__ __forceinline__ ushort_t f2b(float f) {
    uint_t u = __float_as_uint(f);
    return (ushort_t)((u + 0x7fffu + ((u >> 16) & 1u)) >> 16);
}
__device__ __forceinline__ uint_t pack2(float lo, float hi) {
    return (uint_t)f2b(lo) | ((uint_t)f2b(hi) << 16);
}
__device__ __forceinline__ float sigm(float x) { return 1.0f / (1.0f + __expf(-x)); }
__device__ __forceinline__ float tanh_fast(float x) {
    float ex = __expf(2.0f * x);
    return 1.0f - 2.0f / (ex + 1.0f);
}

// unpack u32 holding 2 bf16 -> float2
__device__ __forceinline__ floatx2 unpk(uint_t u) {
    floatx2 r;
    r.x = __uint_as_float(u << 16);
    r.y = __uint_as_float(u & 0xffff0000u);
    return r;
}
// packed dual-FMA: a += w * v  (one VALU inst per 2 floats)
__device__ __forceinline__ void pk_fma(floatx2& a, floatx2 w, floatx2 v) {
    asm("v_pk_fma_f32 %0, %1, %2, %0" : "+v"(a) : "v"(w), "v"(v));
}
// accumulate 8 bf16 (uint4) with packed weight w2: 8 unpack + 4 pk_fma
__device__ __forceinline__ void acc8p(floatx2* a, floatx2 w2, uint4 v) {
    pk_fma(a[0], w2, unpk(v.x));
    pk_fma(a[1], w2, unpk(v.y));
    pk_fma(a[2], w2, unpk(v.z));
    pk_fma(a[3], w2, unpk(v.w));
}

// ---------------- CSR build ----------------

__global__ void count_deg(const int* __restrict__ ei, int* __restrict__ cnt) {
    int e = blockIdx.x * 256 + threadIdx.x;
    if (e < EE) atomicAdd(&cnt[ei[EE + e]], 1);
}

__global__ __launch_bounds__(256) void scan1(const int* __restrict__ cnt,
                                             int* __restrict__ offs,
                                             int* __restrict__ bsum) {
    __shared__ int s[256];
    const int t = threadIdx.x, idx = blockIdx.x * 256 + t;
    int x = (idx < NN) ? cnt[idx] : 0;
    s[t] = x;
    __syncthreads();
    for (int o = 1; o < 256; o <<= 1) {
        int v = s[t];
        int u = (t >= o) ? s[t - o] : 0;
        __syncthreads();
        s[t] = v + u;
        __syncthreads();
    }
    if (idx < NN) offs[idx] = s[t] - x;  // block-local exclusive
    if (t == 255) bsum[blockIdx.x] = s[255];
}

// scan3 now also does the cross-block prefix (scan2 fused away)
__global__ __launch_bounds__(256) void scan3(const int* __restrict__ cnt,
                                             const int* __restrict__ bsum,
                                             int* __restrict__ offs,
                                             int* __restrict__ cursor,
                                             float* __restrict__ dis) {
    __shared__ int sb[40];
    __shared__ int pfx;
    const int t = threadIdx.x;
    if (t < 40) sb[t] = bsum[t];
    __syncthreads();
    if (t == 0) {
        int a = 0;
        for (int i = 0; i < blockIdx.x; ++i) a += sb[i];
        pfx = a;
    }
    __syncthreads();
    const int idx = blockIdx.x * 256 + t;
    if (idx < NN) {
        int off = offs[idx] + pfx;
        offs[idx] = off;
        cursor[idx] = off;
        dis[idx] = rsqrtf((float)(cnt[idx] + 1));
    }
    if (idx == 0) offs[NN] = EE;
}

// csr: src index + bf16(dis[src]) weight
__global__ void fill_csr(const int* __restrict__ ei, int* __restrict__ cursor,
                         const float* __restrict__ dis, int* __restrict__ csr_src,
                         ushort_t* __restrict__ csr_w) {
    int e = blockIdx.x * 256 + threadIdx.x;
    if (e < EE) {
        int s = ei[e];
        int d = ei[EE + e];
        int pos = atomicAdd(&cursor[d], 1);
        csr_src[pos] = s;
        csr_w[pos] = f2b(dis[s]);
    }
}

// ---------------- pack x,h -> bf16 + weight transpose (merged) ----------------

__global__ __launch_bounds__(256) void packwt_k(const float* __restrict__ x,
                                                const float* __restrict__ h,
                                                ushort_t* __restrict__ xb,
                                                ushort_t* __restrict__ hb,
                                                const float* __restrict__ Wz,
                                                const float* __restrict__ Wr,
                                                const float* __restrict__ Wc,
                                                ushort_t* __restrict__ Wt_zr,
                                                ushort_t* __restrict__ Wt_c) {
    if (blockIdx.x < 10000) {
        const size_t o = ((size_t)blockIdx.x * 256 + threadIdx.x) * 4;
        float4 vx = *(const float4*)(x + o);
        uint2 px;
        px.x = pack2(vx.x, vx.y);
        px.y = pack2(vx.z, vx.w);
        *(uint2*)(xb + o) = px;
        float4 vh = *(const float4*)(h + o);
        uint2 ph;
        ph.x = pack2(vh.x, vh.y);
        ph.y = pack2(vh.z, vh.w);
        *(uint2*)(hb + o) = ph;
    } else {
        const int col = blockIdx.x - 10000, k = threadIdx.x;
        if (col < 256) {
            float v = (col < 128) ? Wz[(size_t)k * 128 + col]
                                  : Wr[(size_t)k * 128 + col - 128];
            Wt_zr[(size_t)col * 256 + k] = f2b(v);
        } else {
            int c2 = col - 256;
            Wt_c[(size_t)c2 * 256 + k] = f2b(Wc[(size_t)k * 128 + c2]);
        }
    }
}

// ---------------- gather4: 4 edges/iter x 16 lanes x 8 bf16 cols ----------------
// dst[b,n] = dis[n] * ( sum_e dis[s]*src[b,s] + dis[n]*src[b,n] )
// One wave per (b,n). b = blockIdx&7 -> XCD round-robin pins each batch's 5.1 MB
// working set to one XCD's L2 (FETCH ~104 MB vs 309 MB without affinity).
// Group g = lane>>4 owns edge i*4+g; metadata chunk-preloaded coalesced,
// broadcast per-group via ds_bpermute. Math via v_pk_fma_f32 (packed dual FMA).

template <int NB>
__global__ __launch_bounds__(256) void gather4(
    const ushort_t* __restrict__ src0, const ushort_t* __restrict__ src1,
    const int* __restrict__ offs, const int* __restrict__ csr_src,
    const ushort_t* __restrict__ csr_w, const float* __restrict__ dis,
    ushort_t* __restrict__ dst0, ushort_t* __restrict__ dst1) {
    const int tid = threadIdx.x, lane = tid & 63;
    const int b = blockIdx.x & 7;
    const int n = (blockIdx.x >> 3) * 4 + (tid >> 6);
    const int g = lane >> 4, il = lane & 15;
    const ushort_t* base0 = src0 + (size_t)b * NN * 128;
    const ushort_t* base1 = (NB == 2) ? (src1 + (size_t)b * NN * 128) : base0;

    floatx2 a0[4], a1[4];
#pragma unroll
    for (int j = 0; j < 4; ++j) {
        a0[j] = (floatx2){0.f, 0.f};
        a1[j] = (floatx2){0.f, 0.f};
    }

    const float dn = dis[n];
    if (g == 0) {  // self row, weight dn inside the sum
        const floatx2 d2 = {dn, dn};
        const uint_t off = (uint_t)n * 128u + (uint_t)il * 8u;
        uint4 v = *(const uint4*)(base0 + off);
        acc8p(a0, d2, v);
        if (NB == 2) {
            uint4 vv = *(const uint4*)(base1 + off);
            acc8p(a1, d2, vv);
        }
    }

    const int e0 = offs[n], e1 = offs[n + 1];
    for (int ch = e0; ch < e1; ch += 64) {
        const int rem = e1 - ch;
        int idx = 0, wb = 0;
        if (lane < rem) {
            idx = csr_src[ch + lane];
            wb = (int)((uint_t)csr_w[ch + lane] << 16);
        }
        const int m = rem < 64 ? rem : 64;
        const int groups = (m + 3) >> 2;
        int pidx = g * 4;  // bpermute byte index for edge i*4+g
#pragma unroll 4
        for (int i = 0; i < groups; ++i) {
            const int s = __builtin_amdgcn_ds_bpermute(pidx, idx);
            const float w =
                __uint_as_float((uint_t)__builtin_amdgcn_ds_bpermute(pidx, wb));
            pidx += 16;
            const floatx2 w2 = {w, w};
            const uint_t off = (uint_t)s * 128u + (uint_t)il * 8u;
            uint4 v = *(const uint4*)(base0 + off);
            acc8p(a0, w2, v);
            if (NB == 2) {
                uint4 vv = *(const uint4*)(base1 + off);
                acc8p(a1, w2, vv);
            }
        }
    }

    float o0[8], o1[8];
#pragma unroll
    for (int j = 0; j < 4; ++j) {
        o0[2 * j] = a0[j].x;
        o0[2 * j + 1] = a0[j].y;
        o1[2 * j] = a1[j].x;
        o1[2 * j + 1] = a1[j].y;
    }
#pragma unroll
    for (int j = 0; j < 8; ++j) {
        o0[j] *= dn;
        o0[j] += __shfl_xor(o0[j], 16);
        o0[j] += __shfl_xor(o0[j], 32);
    }
    if (NB == 2) {
#pragma unroll
        for (int j = 0; j < 8; ++j) {
            o1[j] *= dn;
            o1[j] += __shfl_xor(o1[j], 16);
            o1[j] += __shfl_xor(o1[j], 32);
        }
    }

    if (lane < 16) {
        const size_t o = ((size_t)b * NN + n) * 128 + (size_t)il * 8;
        uint4 st;
        st.x = pack2(o0[0], o0[1]);
        st.y = pack2(o0[2], o0[3]);
        st.z = pack2(o0[4], o0[5]);
        st.w = pack2(o0[6], o0[7]);
        *(uint4*)(dst0 + o) = st;
        if (NB == 2) {
            uint4 st1;
            st1.x = pack2(o1[0], o1[1]);
            st1.y = pack2(o1[2], o1[3]);
            st1.z = pack2(o1[4], o1[5]);
            st1.w = pack2(o1[6], o1[7]);
            *(uint4*)(dst1 + o) = st1;
        }
    }
}

// ---------------- GEMM 128x128 tile, K=256 = [A1 | A2] @ Wt, fused epilogues ------
// PHASE 0: mode=blockIdx.y (0: z=sigma->z_buf bf16; 1: r=sigma, rh=r*h->rh bf16)
// PHASE 1: mode 2: tanh, GRU blend, LayerNorm -> out f32

template <int PHASE>
__global__ __launch_bounds__(256) void gemm_k(
    const ushort_t* __restrict__ A1, const ushort_t* __restrict__ A2,
    const ushort_t* __restrict__ Wt, const float* __restrict__ bz,
    const float* __restrict__ br, const float* __restrict__ bc,
    const float* __restrict__ h_prev, const ushort_t* __restrict__ z_in,
    const float* __restrict__ gamma, const float* __restrict__ beta,
    ushort_t* __restrict__ z_out, ushort_t* __restrict__ rh_out,
    float* __restrict__ f_out) {
    __shared__ __align__(16) ushort_t As[128 * 72];
    __shared__ __align__(16) ushort_t Bs[128 * 72];
    const int tid = threadIdx.x;
    const int rb0 = blockIdx.x * 128;
    const int mode = (PHASE == 1) ? 2 : blockIdx.y;
    const int cb0 = (mode == 1) ? 128 : 0;

    const int wv = tid >> 6, lane = tid & 63;
    const int l15 = lane & 15, q = lane >> 4;
    const int sr = tid >> 1;
    const int kh = (tid & 1) * 32;

    floatx4 acc[2][8];
#pragma unroll
    for (int i = 0; i < 2; ++i)
#pragma unroll
        for (int j = 0; j < 8; ++j) acc[i][j] = (floatx4){0.f, 0.f, 0.f, 0.f};

    for (int k0 = 0; k0 < 256; k0 += 64) {
        {
            const int kg = k0 + kh;
            const ushort_t* s = (kg < 128) ? (A1 + (size_t)(rb0 + sr) * 128 + kg)
                                           : (A2 + (size_t)(rb0 + sr) * 128 + (kg - 128));
            ushort_t* dst = &As[sr * 72 + kh];
#pragma unroll
            for (int i = 0; i < 4; ++i) *(uint4*)(dst + i * 8) = *(const uint4*)(s + i * 8);
        }
        {
            const ushort_t* s = Wt + (size_t)(cb0 + sr) * 256 + k0 + kh;
            ushort_t* dst = &Bs[sr * 72 + kh];
#pragma unroll
            for (int i = 0; i < 4; ++i) *(uint4*)(dst + i * 8) = *(const uint4*)(s + i * 8);
        }
        __syncthreads();
#pragma unroll
        for (int ks = 0; ks < 2; ++ks) {
            const int ko = ks * 32 + q * 8;
            bf16x8 a0 = *(const bf16x8*)&As[(wv * 32 + l15) * 72 + ko];
            bf16x8 a1 = *(const bf16x8*)&As[(wv * 32 + 16 + l15) * 72 + ko];
#pragma unroll
            for (int j = 0; j < 8; ++j) {
                bf16x8 b = *(const bf16x8*)&Bs[(j * 16 + l15) * 72 + ko];
                acc[0][j] = __builtin_amdgcn_mfma_f32_16x16x32_bf16(a0, b, acc[0][j], 0, 0, 0);
                acc[1][j] = __builtin_amdgcn_mfma_f32_16x16x32_bf16(a1, b, acc[1][j], 0, 0, 0);
            }
        }
        __syncthreads();
    }

    // C/D: col = j*16 + l15, row = rb0 + wv*32 + i*16 + q*4 + v
    if (mode == 0) {
        float bv[8];
#pragma unroll
        for (int j = 0; j < 8; ++j) bv[j] = bz[j * 16 + l15];
#pragma unroll
        for (int i = 0; i < 2; ++i)
#pragma unroll
            for (int j = 0; j < 8; ++j)
#pragma unroll
                for (int v = 0; v < 4; ++v) {
                    int row = rb0 + wv * 32 + i * 16 + q * 4 + v;
                    z_out[(size_t)row * 128 + j * 16 + l15] = f2b(sigm(acc[i][j][v] + bv[j]));
                }
    } else if (mode == 1) {
        float bv[8];
#pragma unroll
        for (int j = 0; j < 8; ++j) bv[j] = br[j * 16 + l15];
#pragma unroll
        for (int i = 0; i < 2; ++i)
#pragma unroll
            for (int j = 0; j < 8; ++j)
#pragma unroll
                for (int v = 0; v < 4; ++v) {
                    int row = rb0 + wv * 32 + i * 16 + q * 4 + v;
                    float r = sigm(acc[i][j][v] + bv[j]);
                    float hh = h_prev[(size_t)row * 128 + j * 16 + l15];
                    rh_out[(size_t)row * 128 + j * 16 + l15] = f2b(r * hh);
                }
    } else {
        float bv[8], gv[8], bev[8];
#pragma unroll
        for (int j = 0; j < 8; ++j) {
            bv[j] = bc[j * 16 + l15];
            gv[j] = gamma[j * 16 + l15];
            bev[j] = beta[j * 16 + l15];
        }
#pragma unroll
        for (int i = 0; i < 2; ++i)
#pragma unroll
            for (int v = 0; v < 4; ++v) {
                const int row = rb0 + wv * 32 + i * 16 + q * 4 + v;
                float hn[8];
                float s = 0.f;
#pragma unroll
                for (int j = 0; j < 8; ++j) {
                    float hc = tanh_fast(acc[i][j][v] + bv[j]);
                    float zz = b2f((uint_t)z_in[(size_t)row * 128 + j * 16 + l15]);
                    float hh = h_prev[(size_t)row * 128 + j * 16 + l15];
                    hn[j] = (1.0f - zz) * hh + zz * hc;
                    s += hn[j];
                }
#pragma unroll
                for (int o = 8; o > 0; o >>= 1) s += __shfl_xor(s, o);  // 16-lane quad
                float mu = s * (1.0f / 128.0f);
                float vv = 0.f;
#pragma unroll
                for (int j = 0; j < 8; ++j) {
                    float d = hn[j] - mu;
                    vv += d * d;
                }
#pragma unroll
                for (int o = 8; o > 0; o >>= 1) vv += __shfl_xor(vv, o);
                float inv = rsqrtf(vv * (1.0f / 128.0f) + LN_EPS);
#pragma unroll
                for (int j = 0; j < 8; ++j)
                    f_out[(size_t)row * 128 + j * 16 + l15] =
                        (hn[j] - mu) * inv * gv[j] + bev[j];
            }
    }
}

// ---------------- launch ----------------

extern "C" void kernel_launch(void* const* d_in, const int* in_sizes, int n_in,
                              void* d_out, int out_size, void* d_ws, size_t ws_size,
                              hipStream_t stream) {
    const float* x = (const float*)d_in[0];
    const int* ei = (const int*)d_in[1];
    const float* h = (const float*)d_in[2];
    const float* Wz = (const float*)d_in[3];
    const float* bz = (const float*)d_in[4];
    const float* Wr = (const float*)d_in[5];
    const float* br = (const float*)d_in[6];
    const float* Wc = (const float*)d_in[7];
    const float* bcv = (const float*)d_in[8];
    const float* gamma = (const float*)d_in[9];
    const float* beta = (const float*)d_in[10];
    float* out = (float*)d_out;

    char* w = (char*)d_ws;
    int* offs = (int*)(w + 0);                    //    40,004 B
    float* dis = (float*)(w + 40960);             //    40,000 B
    int* csr_src = (int*)(w + 81920);             //   640,000 B
    ushort_t* csr_w = (ushort_t*)(w + 721920);    //   320,000 B
    ushort_t* Wt_zr = (ushort_t*)(w + 1041920);   //   131,072 B
    ushort_t* Wt_c = (ushort_t*)(w + 1172992);    //    65,536 B
    ushort_t* xb = (ushort_t*)(w + 1239040);      // 20,480,000 B
    ushort_t* hb = (ushort_t*)(w + 21719040);     // 20,480,000 B
    ushort_t* agg_x = (ushort_t*)(w + 42199040);  // 20,480,000 B
    ushort_t* agg_h = (ushort_t*)(w + 62679040);  // 20,480,000 B -> end 83,159,040
    // aliases (strict lifetime reuse on one stream):
    int* cnt = (int*)(w + 1239040);     // dead after fill_csr, before packwt_k
    int* cursor = (int*)(w + 1280000);  // dead after fill_csr
    int* bsum = (int*)(w + 1320000);    // dead after scan3
    ushort_t* z_buf = xb;      // xb dead after gather4<2>; written by gemm<0>
    ushort_t* rh_bf = hb;      // hb dead after gather4<2>; written by gemm<0>
    ushort_t* agg_rh = agg_h;  // agg_h dead after gemm<0>

    hipMemsetAsync(cnt, 0, NN * sizeof(int), stream);
    count_deg<<<EE / 256, 256, 0, stream>>>(ei, cnt);
    scan1<<<40, 256, 0, stream>>>(cnt, offs, bsum);
    scan3<<<40, 256, 0, stream>>>(cnt, bsum, offs, cursor, dis);
    fill_csr<<<EE / 256, 256, 0, stream>>>(ei, cursor, dis, csr_src, csr_w);
    packwt_k<<<10384, 256, 0, stream>>>(x, h, xb, hb, Wz, Wr, Wc, Wt_zr, Wt_c);

    // agg_x, agg_h in one fused pass
    gather4<2><<<(BB * NN) / 4, 256, 0, stream>>>(xb, hb, offs, csr_src, csr_w, dis,
                                                  agg_x, agg_h);
    // z (y=0) and rh (y=1) from one GEMM over [agg_x|agg_h]
    gemm_k<0><<<dim3(80000 / 128, 2), 256, 0, stream>>>(
        agg_x, agg_h, Wt_zr, bz, br, bcv, h, (const ushort_t*)0, gamma, beta,
        z_buf, rh_bf, (float*)0);
    gather4<1><<<(BB * NN) / 4, 256, 0, stream>>>(rh_bf, (const ushort_t*)0, offs,
                                                  csr_src, csr_w, dis, agg_rh,
                                                  (ushort_t*)0);
    // out = LN(GRU(tanh([agg_x|agg_rh]@Wc + bc)))
    gemm_k<1><<<dim3(80000 / 128, 1), 256, 0, stream>>>(
        agg_x, agg_rh, Wt_c, bz, br, bcv, h, z_buf, gamma, beta,
        (ushort_t*)0, (ushort_t*)0, out);
}

// Round 3
// 316.727 us; speedup vs baseline: 1.2108x; 1.0420x over previous
//
#include <hip/hip_runtime.h>

#define NN 10000
#define BB 8
#define EE 160000
#define DH 128
#define LN_EPS 1e-5f

typedef unsigned short ushort_t;
typedef unsigned int uint_t;

typedef __bf16 bf16x8 __attribute__((ext_vector_type(8)));
typedef float floatx4 __attribute__((ext_vector_type(4)));
typedef float floatx2 __attribute__((ext_vector_type(2)));

__device__ __forceinline__ float b2f(uint_t u) { return __uint_as_float(u << 16); }
__device__ __forceinline__ ushort_t f2b(float f) {
    uint_t u = __float_as_uint(f);
    return (ushort_t)((u + 0x7fffu + ((u >> 16) & 1u)) >> 16);
}
__device__ __forceinline__ uint_t pack2(float lo, float hi) {
    return (uint_t)f2b(lo) | ((uint_t)f2b(hi) << 16);
}
__device__ __forceinline__ float sigm(float x) { return 1.0f / (1.0f + __expf(-x)); }
__device__ __forceinline__ float tanh_fast(float x) {
    float ex = __expf(2.0f * x);
    return 1.0f - 2.0f / (ex + 1.0f);
}

// unpack u32 holding 2 bf16 -> float2
__device__ __forceinline__ floatx2 unpk(uint_t u) {
    floatx2 r;
    r.x = __uint_as_float(u << 16);
    r.y = __uint_as_float(u & 0xffff0000u);
    return r;
}
// packed dual-FMA: a += w * v  (one VALU inst per 2 floats)
__device__ __forceinline__ void pk_fma(floatx2& a, floatx2 w, floatx2 v) {
    asm("v_pk_fma_f32 %0, %1, %2, %0" : "+v"(a) : "v"(w), "v"(v));
}
// accumulate 8 bf16 (uint4) with packed weight w2: 8 unpack + 4 pk_fma
__device__ __forceinline__ void acc8p(floatx2* a, floatx2 w2, uint4 v) {
    pk_fma(a[0], w2, unpk(v.x));
    pk_fma(a[1], w2, unpk(v.y));
    pk_fma(a[2], w2, unpk(v.z));
    pk_fma(a[3], w2, unpk(v.w));
}

// ---------------- CSR build ----------------

__global__ void count_deg(const int* __restrict__ ei, int* __restrict__ cnt) {
    int e = blockIdx.x * 256 + threadIdx.x;
    if (e < EE) atomicAdd(&cnt[ei[EE + e]], 1);
}

__global__ __launch_bounds__(256) void scan1(const int* __restrict__ cnt,
                                             int* __restrict__ offs,
                                             int* __restrict__ bsum) {
    __shared__ int s[256];
    const int t = threadIdx.x, idx = blockIdx.x * 256 + t;
    int x = (idx < NN) ? cnt[idx] : 0;
    s[t] = x;
    __syncthreads();
    for (int o = 1; o < 256; o <<= 1) {
        int v = s[t];
        int u = (t >= o) ? s[t - o] : 0;
        __syncthreads();
        s[t] = v + u;
        __syncthreads();
    }
    if (idx < NN) offs[idx] = s[t] - x;  // block-local exclusive
    if (t == 255) bsum[blockIdx.x] = s[255];
}

// scan3 also does the cross-block prefix (scan2 fused away)
__global__ __launch_bounds__(256) void scan3(const int* __restrict__ cnt,
                                             const int* __restrict__ bsum,
                                             int* __restrict__ offs,
                                             int* __restrict__ cursor,
                                             float* __restrict__ dis) {
    __shared__ int sb[40];
    __shared__ int pfx;
    const int t = threadIdx.x;
    if (t < 40) sb[t] = bsum[t];
    __syncthreads();
    if (t == 0) {
        int a = 0;
        for (int i = 0; i < blockIdx.x; ++i) a += sb[i];
        pfx = a;
    }
    __syncthreads();
    const int idx = blockIdx.x * 256 + t;
    if (idx < NN) {
        int off = offs[idx] + pfx;
        offs[idx] = off;
        cursor[idx] = off;
        dis[idx] = rsqrtf((float)(cnt[idx] + 1));
    }
    if (idx == 0) offs[NN] = EE;
}

// csr: src index + bf16(dis[src]) weight
__global__ void fill_csr(const int* __restrict__ ei, int* __restrict__ cursor,
                         const float* __restrict__ dis, int* __restrict__ csr_src,
                         ushort_t* __restrict__ csr_w) {
    int e = blockIdx.x * 256 + threadIdx.x;
    if (e < EE) {
        int s = ei[e];
        int d = ei[EE + e];
        int pos = atomicAdd(&cursor[d], 1);
        csr_src[pos] = s;
        csr_w[pos] = f2b(dis[s]);
    }
}

// ---------------- pack x,h -> bf16 + weight transpose (merged) ----------------

__global__ __launch_bounds__(256) void packwt_k(const float* __restrict__ x,
                                                const float* __restrict__ h,
                                                ushort_t* __restrict__ xb,
                                                ushort_t* __restrict__ hb,
                                                const float* __restrict__ Wz,
                                                const float* __restrict__ Wr,
                                                const float* __restrict__ Wc,
                                                ushort_t* __restrict__ Wt_zr,
                                                ushort_t* __restrict__ Wt_c) {
    if (blockIdx.x < 10000) {
        const size_t o = ((size_t)blockIdx.x * 256 + threadIdx.x) * 4;
        float4 vx = *(const float4*)(x + o);
        uint2 px;
        px.x = pack2(vx.x, vx.y);
        px.y = pack2(vx.z, vx.w);
        *(uint2*)(xb + o) = px;
        float4 vh = *(const float4*)(h + o);
        uint2 ph;
        ph.x = pack2(vh.x, vh.y);
        ph.y = pack2(vh.z, vh.w);
        *(uint2*)(hb + o) = ph;
    } else {
        const int col = blockIdx.x - 10000, k = threadIdx.x;
        if (col < 256) {
            float v = (col < 128) ? Wz[(size_t)k * 128 + col]
                                  : Wr[(size_t)k * 128 + col - 128];
            Wt_zr[(size_t)col * 256 + k] = f2b(v);
        } else {
            int c2 = col - 256;
            Wt_c[(size_t)c2 * 256 + k] = f2b(Wc[(size_t)k * 128 + c2]);
        }
    }
}

// ---------------- gather4: 4 edges/iter x 16 lanes x 8 bf16 cols ----------------
// dst[b,n] = dis[n] * ( sum_e dis[s]*src[b,s] + dis[n]*src[b,n] )
// One wave per (b,n). b = blockIdx&7 -> XCD round-robin pins each batch's 5.1 MB
// working set to one XCD's L2 (FETCH ~104 MB vs 309 MB without affinity).

template <int NB>
__global__ __launch_bounds__(256) void gather4(
    const ushort_t* __restrict__ src0, const ushort_t* __restrict__ src1,
    const int* __restrict__ offs, const int* __restrict__ csr_src,
    const ushort_t* __restrict__ csr_w, const float* __restrict__ dis,
    ushort_t* __restrict__ dst0, ushort_t* __restrict__ dst1) {
    const int tid = threadIdx.x, lane = tid & 63;
    const int b = blockIdx.x & 7;
    const int n = (blockIdx.x >> 3) * 4 + (tid >> 6);
    const int g = lane >> 4, il = lane & 15;
    const ushort_t* base0 = src0 + (size_t)b * NN * 128;
    const ushort_t* base1 = (NB == 2) ? (src1 + (size_t)b * NN * 128) : base0;

    floatx2 a0[4], a1[4];
#pragma unroll
    for (int j = 0; j < 4; ++j) {
        a0[j] = (floatx2){0.f, 0.f};
        a1[j] = (floatx2){0.f, 0.f};
    }

    const float dn = dis[n];
    if (g == 0) {  // self row, weight dn inside the sum
        const floatx2 d2 = {dn, dn};
        const uint_t off = (uint_t)n * 128u + (uint_t)il * 8u;
        uint4 v = *(const uint4*)(base0 + off);
        acc8p(a0, d2, v);
        if (NB == 2) {
            uint4 vv = *(const uint4*)(base1 + off);
            acc8p(a1, d2, vv);
        }
    }

    const int e0 = offs[n], e1 = offs[n + 1];
    for (int ch = e0; ch < e1; ch += 64) {
        const int rem = e1 - ch;
        int idx = 0, wb = 0;
        if (lane < rem) {
            idx = csr_src[ch + lane];
            wb = (int)((uint_t)csr_w[ch + lane] << 16);
        }
        const int m = rem < 64 ? rem : 64;
        const int groups = (m + 3) >> 2;
        int pidx = g * 4;  // bpermute byte index for edge i*4+g
#pragma unroll 4
        for (int i = 0; i < groups; ++i) {
            const int s = __builtin_amdgcn_ds_bpermute(pidx, idx);
            const float w =
                __uint_as_float((uint_t)__builtin_amdgcn_ds_bpermute(pidx, wb));
            pidx += 16;
            const floatx2 w2 = {w, w};
            const uint_t off = (uint_t)s * 128u + (uint_t)il * 8u;
            uint4 v = *(const uint4*)(base0 + off);
            acc8p(a0, w2, v);
            if (NB == 2) {
                uint4 vv = *(const uint4*)(base1 + off);
                acc8p(a1, w2, vv);
            }
        }
    }

    float o0[8], o1[8];
#pragma unroll
    for (int j = 0; j < 4; ++j) {
        o0[2 * j] = a0[j].x;
        o0[2 * j + 1] = a0[j].y;
        o1[2 * j] = a1[j].x;
        o1[2 * j + 1] = a1[j].y;
    }
#pragma unroll
    for (int j = 0; j < 8; ++j) {
        o0[j] *= dn;
        o0[j] += __shfl_xor(o0[j], 16);
        o0[j] += __shfl_xor(o0[j], 32);
    }
    if (NB == 2) {
#pragma unroll
        for (int j = 0; j < 8; ++j) {
            o1[j] *= dn;
            o1[j] += __shfl_xor(o1[j], 16);
            o1[j] += __shfl_xor(o1[j], 32);
        }
    }

    if (lane < 16) {
        const size_t o = ((size_t)b * NN + n) * 128 + (size_t)il * 8;
        uint4 st;
        st.x = pack2(o0[0], o0[1]);
        st.y = pack2(o0[2], o0[3]);
        st.z = pack2(o0[4], o0[5]);
        st.w = pack2(o0[6], o0[7]);
        *(uint4*)(dst0 + o) = st;
        if (NB == 2) {
            uint4 st1;
            st1.x = pack2(o1[0], o1[1]);
            st1.y = pack2(o1[2], o1[3]);
            st1.z = pack2(o1[4], o1[5]);
            st1.w = pack2(o1[6], o1[7]);
            *(uint4*)(dst1 + o) = st1;
        }
    }
}

// ---------------- GEMM 128x128 tile, K=256 = [A1 | A2] @ Wt, fused epilogues ------
// 512 threads / 8 waves: wave w owns rows w*16..w*16+15 (acc = 8 x floatx4).
// Register-prefetch pipeline: k0+1's global loads issued before k0's MFMA compute,
// consumed by ds_write after the next barrier -> HBM latency hidden under compute.
// PHASE 0: mode=blockIdx.y (0: z=sigma->z_buf bf16; 1: r=sigma, rh=r*h->rh bf16)
// PHASE 1: mode 2: tanh, GRU blend, LayerNorm -> out f32

template <int PHASE>
__global__ __launch_bounds__(512) void gemm_k(
    const ushort_t* __restrict__ A1, const ushort_t* __restrict__ A2,
    const ushort_t* __restrict__ Wt, const float* __restrict__ bz,
    const float* __restrict__ br, const float* __restrict__ bc,
    const float* __restrict__ h_prev, const ushort_t* __restrict__ z_in,
    const float* __restrict__ gamma, const float* __restrict__ beta,
    ushort_t* __restrict__ z_out, ushort_t* __restrict__ rh_out,
    float* __restrict__ f_out) {
    __shared__ __align__(16) ushort_t As[128 * 72];
    __shared__ __align__(16) ushort_t Bs[128 * 72];
    const int tid = threadIdx.x;
    const int rb0 = blockIdx.x * 128;
    const int mode = (PHASE == 1) ? 2 : blockIdx.y;
    const int cb0 = (mode == 1) ? 128 : 0;

    const int wv = tid >> 6, lane = tid & 63;
    const int l15 = lane & 15, q = lane >> 4;
    const int sr = tid >> 2;        // 0..127: A row / B col staged by this thread
    const int kh = (tid & 3) * 16;  // 16-element K chunk

    floatx4 acc[8];
#pragma unroll
    for (int j = 0; j < 8; ++j) acc[j] = (floatx4){0.f, 0.f, 0.f, 0.f};

    uint4 pa0, pa1, pb0, pb1;  // prefetch registers (one K-step tile slice)
#define LOAD_AB(k0)                                                                   \
    {                                                                                 \
        const int kg = (k0) + kh;                                                     \
        const ushort_t* sA = (kg < 128)                                               \
                                 ? (A1 + (size_t)(rb0 + sr) * 128 + kg)               \
                                 : (A2 + (size_t)(rb0 + sr) * 128 + (kg - 128));      \
        pa0 = *(const uint4*)(sA);                                                    \
        pa1 = *(const uint4*)(sA + 8);                                                \
        const ushort_t* sB = Wt + (size_t)(cb0 + sr) * 256 + (k0) + kh;               \
        pb0 = *(const uint4*)(sB);                                                    \
        pb1 = *(const uint4*)(sB + 8);                                                \
    }

    LOAD_AB(0);
#pragma unroll
    for (int t = 0; t < 4; ++t) {
        if (t) __syncthreads();  // all waves done reading previous tile
        *(uint4*)(&As[sr * 72 + kh]) = pa0;
        *(uint4*)(&As[sr * 72 + kh + 8]) = pa1;
        *(uint4*)(&Bs[sr * 72 + kh]) = pb0;
        *(uint4*)(&Bs[sr * 72 + kh + 8]) = pb1;
        __syncthreads();
        if (t < 3) LOAD_AB((t + 1) * 64);  // prefetch next tile under compute
#pragma unroll
        for (int ks = 0; ks < 2; ++ks) {
            const int ko = ks * 32 + q * 8;
            bf16x8 a0 = *(const bf16x8*)&As[(wv * 16 + l15) * 72 + ko];
#pragma unroll
            for (int j = 0; j < 8; ++j) {
                bf16x8 b = *(const bf16x8*)&Bs[(j * 16 + l15) * 72 + ko];
                acc[j] = __builtin_amdgcn_mfma_f32_16x16x32_bf16(a0, b, acc[j], 0, 0, 0);
            }
        }
    }
#undef LOAD_AB

    // C/D: col = j*16 + l15, row = rb0 + wv*16 + q*4 + v
    if (mode == 0) {
        float bv[8];
#pragma unroll
        for (int j = 0; j < 8; ++j) bv[j] = bz[j * 16 + l15];
#pragma unroll
        for (int j = 0; j < 8; ++j)
#pragma unroll
            for (int v = 0; v < 4; ++v) {
                int row = rb0 + wv * 16 + q * 4 + v;
                z_out[(size_t)row * 128 + j * 16 + l15] = f2b(sigm(acc[j][v] + bv[j]));
            }
    } else if (mode == 1) {
        float bv[8];
#pragma unroll
        for (int j = 0; j < 8; ++j) bv[j] = br[j * 16 + l15];
#pragma unroll
        for (int j = 0; j < 8; ++j)
#pragma unroll
            for (int v = 0; v < 4; ++v) {
                int row = rb0 + wv * 16 + q * 4 + v;
                float r = sigm(acc[j][v] + bv[j]);
                float hh = h_prev[(size_t)row * 128 + j * 16 + l15];
                rh_out[(size_t)row * 128 + j * 16 + l15] = f2b(r * hh);
            }
    } else {
        float bv[8], gv[8], bev[8];
#pragma unroll
        for (int j = 0; j < 8; ++j) {
            bv[j] = bc[j * 16 + l15];
            gv[j] = gamma[j * 16 + l15];
            bev[j] = beta[j * 16 + l15];
        }
#pragma unroll
        for (int v = 0; v < 4; ++v) {
            const int row = rb0 + wv * 16 + q * 4 + v;
            float hn[8];
            float s = 0.f;
#pragma unroll
            for (int j = 0; j < 8; ++j) {
                float hc = tanh_fast(acc[j][v] + bv[j]);
                float zz = b2f((uint_t)z_in[(size_t)row * 128 + j * 16 + l15]);
                float hh = h_prev[(size_t)row * 128 + j * 16 + l15];
                hn[j] = (1.0f - zz) * hh + zz * hc;
                s += hn[j];
            }
#pragma unroll
            for (int o = 8; o > 0; o >>= 1) s += __shfl_xor(s, o);  // 16-lane quad
            float mu = s * (1.0f / 128.0f);
            float vv = 0.f;
#pragma unroll
            for (int j = 0; j < 8; ++j) {
                float d = hn[j] - mu;
                vv += d * d;
            }
#pragma unroll
            for (int o = 8; o > 0; o >>= 1) vv += __shfl_xor(vv, o);
            float inv = rsqrtf(vv * (1.0f / 128.0f) + LN_EPS);
#pragma unroll
            for (int j = 0; j < 8; ++j)
                f_out[(size_t)row * 128 + j * 16 + l15] =
                    (hn[j] - mu) * inv * gv[j] + bev[j];
        }
    }
}

// ---------------- launch ----------------

extern "C" void kernel_launch(void* const* d_in, const int* in_sizes, int n_in,
                              void* d_out, int out_size, void* d_ws, size_t ws_size,
                              hipStream_t stream) {
    const float* x = (const float*)d_in[0];
    const int* ei = (const int*)d_in[1];
    const float* h = (const float*)d_in[2];
    const float* Wz = (const float*)d_in[3];
    const float* bz = (const float*)d_in[4];
    const float* Wr = (const float*)d_in[5];
    const float* br = (const float*)d_in[6];
    const float* Wc = (const float*)d_in[7];
    const float* bcv = (const float*)d_in[8];
    const float* gamma = (const float*)d_in[9];
    const float* beta = (const float*)d_in[10];
    float* out = (float*)d_out;

    char* w = (char*)d_ws;
    int* offs = (int*)(w + 0);                    //    40,004 B
    float* dis = (float*)(w + 40960);             //    40,000 B
    int* csr_src = (int*)(w + 81920);             //   640,000 B
    ushort_t* csr_w = (ushort_t*)(w + 721920);    //   320,000 B
    ushort_t* Wt_zr = (ushort_t*)(w + 1041920);   //   131,072 B
    ushort_t* Wt_c = (ushort_t*)(w + 1172992);    //    65,536 B
    ushort_t* xb = (ushort_t*)(w + 1239040);      // 20,480,000 B
    ushort_t* hb = (ushort_t*)(w + 21719040);     // 20,480,000 B
    ushort_t* agg_x = (ushort_t*)(w + 42199040);  // 20,480,000 B
    ushort_t* agg_h = (ushort_t*)(w + 62679040);  // 20,480,000 B -> end 83,159,040
    // aliases (strict lifetime reuse on one stream):
    int* cnt = (int*)(w + 1239040);     // dead after fill_csr, before packwt_k
    int* cursor = (int*)(w + 1280000);  // dead after fill_csr
    int* bsum = (int*)(w + 1320000);    // dead after scan3
    ushort_t* z_buf = xb;      // xb dead after gather4<2>; written by gemm<0>
    ushort_t* rh_bf = hb;      // hb dead after gather4<2>; written by gemm<0>
    ushort_t* agg_rh = agg_h;  // agg_h dead after gemm<0>

    hipMemsetAsync(cnt, 0, NN * sizeof(int), stream);
    count_deg<<<EE / 256, 256, 0, stream>>>(ei, cnt);
    scan1<<<40, 256, 0, stream>>>(cnt, offs, bsum);
    scan3<<<40, 256, 0, stream>>>(cnt, bsum, offs, cursor, dis);
    fill_csr<<<EE / 256, 256, 0, stream>>>(ei, cursor, dis, csr_src, csr_w);
    packwt_k<<<10384, 256, 0, stream>>>(x, h, xb, hb, Wz, Wr, Wc, Wt_zr, Wt_c);

    // agg_x, agg_h in one fused pass
    gather4<2><<<(BB * NN) / 4, 256, 0, stream>>>(xb, hb, offs, csr_src, csr_w, dis,
                                                  agg_x, agg_h);
    // z (y=0) and rh (y=1) from one GEMM over [agg_x|agg_h]
    gemm_k<0><<<dim3(80000 / 128, 2), 512, 0, stream>>>(
        agg_x, agg_h, Wt_zr, bz, br, bcv, h, (const ushort_t*)0, gamma, beta,
        z_buf, rh_bf, (float*)0);
    gather4<1><<<(BB * NN) / 4, 256, 0, stream>>>(rh_bf, (const ushort_t*)0, offs,
                                                  csr_src, csr_w, dis, agg_rh,
                                                  (ushort_t*)0);
    // out = LN(GRU(tanh([agg_x|agg_rh]@Wc + bc)))
    gemm_k<1><<<dim3(80000 / 128, 1), 512, 0, stream>>>(
        agg_x, agg_rh, Wt_c, bz, br, bcv, h, z_buf, gamma, beta,
        (ushort_t*)0, (ushort_t*)0, out);
}

// Round 5
// 302.533 us; speedup vs baseline: 1.2677x; 1.0469x over previous
//
#include <hip/hip_runtime.h>

#define NN 10000
#define BB 8
#define EE 160000
#define DH 128
#define LN_EPS 1e-5f

typedef unsigned short ushort_t;
typedef unsigned int uint_t;

typedef __bf16 bf16x8 __attribute__((ext_vector_type(8)));
typedef float floatx4 __attribute__((ext_vector_type(4)));
typedef float floatx2 __attribute__((ext_vector_type(2)));

__device__ __forceinline__ float b2f(uint_t u) { return __uint_as_float(u << 16); }
__device__ __forceinline__ ushort_t f2b(float f) {
    uint_t u = __float_as_uint(f);
    return (ushort_t)((u + 0x7fffu + ((u >> 16) & 1u)) >> 16);
}
__device__ __forceinline__ uint_t pack2(float lo, float hi) {
    return (uint_t)f2b(lo) | ((uint_t)f2b(hi) << 16);
}
__device__ __forceinline__ float sigm(float x) { return 1.0f / (1.0f + __expf(-x)); }
__device__ __forceinline__ float tanh_fast(float x) {
    float ex = __expf(2.0f * x);
    return 1.0f - 2.0f / (ex + 1.0f);
}

// unpack u32 holding 2 bf16 -> float2
__device__ __forceinline__ floatx2 unpk(uint_t u) {
    floatx2 r;
    r.x = __uint_as_float(u << 16);
    r.y = __uint_as_float(u & 0xffff0000u);
    return r;
}
// packed dual-FMA: a += w * v  (one VALU inst per 2 floats)
__device__ __forceinline__ void pk_fma(floatx2& a, floatx2 w, floatx2 v) {
    asm("v_pk_fma_f32 %0, %1, %2, %0" : "+v"(a) : "v"(w), "v"(v));
}
// accumulate 8 bf16 (uint4) with packed weight w2: 8 unpack + 4 pk_fma
__device__ __forceinline__ void acc8p(floatx2* a, floatx2 w2, uint4 v) {
    pk_fma(a[0], w2, unpk(v.x));
    pk_fma(a[1], w2, unpk(v.y));
    pk_fma(a[2], w2, unpk(v.z));
    pk_fma(a[3], w2, unpk(v.w));
}

// ---------------- CSR build ----------------

__global__ void count_deg(const int* __restrict__ ei, int* __restrict__ cnt) {
    int e = blockIdx.x * 256 + threadIdx.x;
    if (e < EE) atomicAdd(&cnt[ei[EE + e]], 1);
}

__global__ __launch_bounds__(256) void scan1(const int* __restrict__ cnt,
                                             int* __restrict__ offs,
                                             int* __restrict__ bsum) {
    __shared__ int s[256];
    const int t = threadIdx.x, idx = blockIdx.x * 256 + t;
    int x = (idx < NN) ? cnt[idx] : 0;
    s[t] = x;
    __syncthreads();
    for (int o = 1; o < 256; o <<= 1) {
        int v = s[t];
        int u = (t >= o) ? s[t - o] : 0;
        __syncthreads();
        s[t] = v + u;
        __syncthreads();
    }
    if (idx < NN) offs[idx] = s[t] - x;  // block-local exclusive
    if (t == 255) bsum[blockIdx.x] = s[255];
}

// scan3 also does the cross-block prefix (scan2 fused away)
__global__ __launch_bounds__(256) void scan3(const int* __restrict__ cnt,
                                             const int* __restrict__ bsum,
                                             int* __restrict__ offs,
                                             int* __restrict__ cursor,
                                             float* __restrict__ dis) {
    __shared__ int sb[40];
    __shared__ int pfx;
    const int t = threadIdx.x;
    if (t < 40) sb[t] = bsum[t];
    __syncthreads();
    if (t == 0) {
        int a = 0;
        for (int i = 0; i < blockIdx.x; ++i) a += sb[i];
        pfx = a;
    }
    __syncthreads();
    const int idx = blockIdx.x * 256 + t;
    if (idx < NN) {
        int off = offs[idx] + pfx;
        offs[idx] = off;
        cursor[idx] = off;
        dis[idx] = rsqrtf((float)(cnt[idx] + 1));
    }
    if (idx == 0) offs[NN] = EE;
}

// csr: src index + bf16(dis[src]) weight
__global__ void fill_csr(const int* __restrict__ ei, int* __restrict__ cursor,
                         const float* __restrict__ dis, int* __restrict__ csr_src,
                         ushort_t* __restrict__ csr_w) {
    int e = blockIdx.x * 256 + threadIdx.x;
    if (e < EE) {
        int s = ei[e];
        int d = ei[EE + e];
        int pos = atomicAdd(&cursor[d], 1);
        csr_src[pos] = s;
        csr_w[pos] = f2b(dis[s]);
    }
}

// ---------------- pack x,h -> bf16 + weight transpose (merged) ----------------

__global__ __launch_bounds__(256) void packwt_k(const float* __restrict__ x,
                                                const float* __restrict__ h,
                                                ushort_t* __restrict__ xb,
                                                ushort_t* __restrict__ hb,
                                                const float* __restrict__ Wz,
                                                const float* __restrict__ Wr,
                                                const float* __restrict__ Wc,
                                                ushort_t* __restrict__ Wt_zr,
                                                ushort_t* __restrict__ Wt_c) {
    if (blockIdx.x < 10000) {
        const size_t o = ((size_t)blockIdx.x * 256 + threadIdx.x) * 4;
        float4 vx = *(const float4*)(x + o);
        uint2 px;
        px.x = pack2(vx.x, vx.y);
        px.y = pack2(vx.z, vx.w);
        *(uint2*)(xb + o) = px;
        float4 vh = *(const float4*)(h + o);
        uint2 ph;
        ph.x = pack2(vh.x, vh.y);
        ph.y = pack2(vh.z, vh.w);
        *(uint2*)(hb + o) = ph;
    } else {
        const int col = blockIdx.x - 10000, k = threadIdx.x;
        if (col < 256) {
            float v = (col < 128) ? Wz[(size_t)k * 128 + col]
                                  : Wr[(size_t)k * 128 + col - 128];
            Wt_zr[(size_t)col * 256 + k] = f2b(v);
        } else {
            int c2 = col - 256;
            Wt_c[(size_t)c2 * 256 + k] = f2b(Wc[(size_t)k * 128 + c2]);
        }
    }
}

// ---------------- gather16: 4 waves x 4 nodes/wave, 16 lanes per node -------------
// dst[b,n] = dis[n] * ( sum_e dis[s]*src[b,s] + dis[n]*src[b,n] )
// One 16-lane group per node: lane il owns cols il*8..il*8+7 and accumulates ALL
// edges of its node -> final value is lane-private, NO cross-lane reduce, all 64
// lanes store. b = blockIdx&7 keeps XCD/L2 batch sharding (FETCH ~104 MB).
// Group walks its node's CSR serially; edge idx/w broadcast group-locally via
// ds_bpermute from a 16-edge chunk preloaded in the group's lanes. Loop runs to
// max(deg) over the wave's 4 nodes; finished groups are exec-masked.

template <int NB>
__global__ __launch_bounds__(256) void gather16(
    const ushort_t* __restrict__ src0, const ushort_t* __restrict__ src1,
    const int* __restrict__ offs, const int* __restrict__ csr_src,
    const ushort_t* __restrict__ csr_w, const float* __restrict__ dis,
    ushort_t* __restrict__ dst0, ushort_t* __restrict__ dst1) {
    const int tid = threadIdx.x, lane = tid & 63;
    const int b = blockIdx.x & 7;
    const int g = lane >> 4, il = lane & 15;
    const int ng = (blockIdx.x >> 3) * 16 + (tid >> 6) * 4 + g;  // my group's node
    const ushort_t* base0 = src0 + (size_t)b * NN * 128;
    const ushort_t* base1 = (NB == 2) ? (src1 + (size_t)b * NN * 128) : base0;
    const uint_t cofs = (uint_t)il * 8u;

    floatx2 a0[4], a1[4];
#pragma unroll
    for (int j = 0; j < 4; ++j) {
        a0[j] = (floatx2){0.f, 0.f};
        a1[j] = (floatx2){0.f, 0.f};
    }

    const int e0 = offs[ng], e1 = offs[ng + 1];
    const int deg = e1 - e0;
    const float dn = dis[ng];

    {  // self row, weight dn inside the sum
        const floatx2 d2 = {dn, dn};
        const uint_t off = (uint_t)ng * 128u + cofs;
        acc8p(a0, d2, *(const uint4*)(base0 + off));
        if (NB == 2) acc8p(a1, d2, *(const uint4*)(base1 + off));
    }

    // max degree over the wave's 4 groups -> uniform loop bound
    int mx = deg;
    mx = max(mx, __shfl_xor(mx, 16));
    mx = max(mx, __shfl_xor(mx, 32));
    const int dmax = __builtin_amdgcn_readfirstlane(mx);
    const int pbase = (lane & 48) << 2;  // bpermute byte base of group's lane 0

    for (int ibase = 0; ibase < dmax; ibase += 16) {
        // refill: lane il of group g holds edge e0+ibase+il of node ng
        int idx = 0, wb = 0;
        const int pos = e0 + ibase + il;
        if (pos < e1) {
            idx = csr_src[pos];
            wb = (int)((uint_t)csr_w[pos] << 16);
        }
        const int lim = (dmax - ibase) < 16 ? (dmax - ibase) : 16;
        int pidx = pbase;
#pragma unroll 4
        for (int i = 0; i < lim; ++i) {
            const int s = __builtin_amdgcn_ds_bpermute(pidx, idx);
            const float wgt =
                __uint_as_float((uint_t)__builtin_amdgcn_ds_bpermute(pidx, wb));
            pidx += 4;
            if (ibase + i < deg) {
                const floatx2 w2 = {wgt, wgt};
                const uint_t off = (uint_t)s * 128u + cofs;
                acc8p(a0, w2, *(const uint4*)(base0 + off));
                if (NB == 2) acc8p(a1, w2, *(const uint4*)(base1 + off));
            }
        }
    }

    // lane-private result: scale by dn, pack, store (all 64 lanes)
    const size_t o = ((size_t)b * NN + ng) * 128 + cofs;
    uint4 st;
    st.x = pack2(a0[0].x * dn, a0[0].y * dn);
    st.y = pack2(a0[1].x * dn, a0[1].y * dn);
    st.z = pack2(a0[2].x * dn, a0[2].y * dn);
    st.w = pack2(a0[3].x * dn, a0[3].y * dn);
    *(uint4*)(dst0 + o) = st;
    if (NB == 2) {
        uint4 st1;
        st1.x = pack2(a1[0].x * dn, a1[0].y * dn);
        st1.y = pack2(a1[1].x * dn, a1[1].y * dn);
        st1.z = pack2(a1[2].x * dn, a1[2].y * dn);
        st1.w = pack2(a1[3].x * dn, a1[3].y * dn);
        *(uint4*)(dst1 + o) = st1;
    }
}

// ---------------- GEMM 128x128 tile, K=256 = [A1 | A2] @ Wt, fused epilogues ------
// 512 threads / 8 waves: wave w owns rows w*16..w*16+15 (acc = 8 x floatx4).
// Register-prefetch pipeline: k0+1's global loads issued before k0's MFMA compute,
// consumed by ds_write after the next barrier -> HBM latency hidden under compute.
// PHASE 0: mode=blockIdx.y (0: z=sigma->z_buf bf16; 1: r=sigma, rh=r*h->rh bf16)
// PHASE 1: mode 2: tanh, GRU blend, LayerNorm -> out f32

template <int PHASE>
__global__ __launch_bounds__(512) void gemm_k(
    const ushort_t* __restrict__ A1, const ushort_t* __restrict__ A2,
    const ushort_t* __restrict__ Wt, const float* __restrict__ bz,
    const float* __restrict__ br, const float* __restrict__ bc,
    const float* __restrict__ h_prev, const ushort_t* __restrict__ z_in,
    const float* __restrict__ gamma, const float* __restrict__ beta,
    ushort_t* __restrict__ z_out, ushort_t* __restrict__ rh_out,
    float* __restrict__ f_out) {
    __shared__ __align__(16) ushort_t As[128 * 72];
    __shared__ __align__(16) ushort_t Bs[128 * 72];
    const int tid = threadIdx.x;
    const int rb0 = blockIdx.x * 128;
    const int mode = (PHASE == 1) ? 2 : blockIdx.y;
    const int cb0 = (mode == 1) ? 128 : 0;

    const int wv = tid >> 6, lane = tid & 63;
    const int l15 = lane & 15, q = lane >> 4;
    const int sr = tid >> 2;        // 0..127: A row / B col staged by this thread
    const int kh = (tid & 3) * 16;  // 16-element K chunk

    floatx4 acc[8];
#pragma unroll
    for (int j = 0; j < 8; ++j) acc[j] = (floatx4){0.f, 0.f, 0.f, 0.f};

    uint4 pa0, pa1, pb0, pb1;  // prefetch registers (one K-step tile slice)
#define LOAD_AB(k0)                                                                   \
    {                                                                                 \
        const int kg = (k0) + kh;                                                     \
        const ushort_t* sA = (kg < 128)                                               \
                                 ? (A1 + (size_t)(rb0 + sr) * 128 + kg)               \
                                 : (A2 + (size_t)(rb0 + sr) * 128 + (kg - 128));      \
        pa0 = *(const uint4*)(sA);                                                    \
        pa1 = *(const uint4*)(sA + 8);                                                \
        const ushort_t* sB = Wt + (size_t)(cb0 + sr) * 256 + (k0) + kh;               \
        pb0 = *(const uint4*)(sB);                                                    \
        pb1 = *(const uint4*)(sB + 8);                                                \
    }

    LOAD_AB(0);
#pragma unroll
    for (int t = 0; t < 4; ++t) {
        if (t) __syncthreads();  // all waves done reading previous tile
        *(uint4*)(&As[sr * 72 + kh]) = pa0;
        *(uint4*)(&As[sr * 72 + kh + 8]) = pa1;
        *(uint4*)(&Bs[sr * 72 + kh]) = pb0;
        *(uint4*)(&Bs[sr * 72 + kh + 8]) = pb1;
        __syncthreads();
        if (t < 3) LOAD_AB((t + 1) * 64);  // prefetch next tile under compute
#pragma unroll
        for (int ks = 0; ks < 2; ++ks) {
            const int ko = ks * 32 + q * 8;
            bf16x8 a0 = *(const bf16x8*)&As[(wv * 16 + l15) * 72 + ko];
#pragma unroll
            for (int j = 0; j < 8; ++j) {
                bf16x8 b = *(const bf16x8*)&Bs[(j * 16 + l15) * 72 + ko];
                acc[j] = __builtin_amdgcn_mfma_f32_16x16x32_bf16(a0, b, acc[j], 0, 0, 0);
            }
        }
    }
#undef LOAD_AB

    // C/D: col = j*16 + l15, row = rb0 + wv*16 + q*4 + v
    if (mode == 0) {
        float bv[8];
#pragma unroll
        for (int j = 0; j < 8; ++j) bv[j] = bz[j * 16 + l15];
#pragma unroll
        for (int j = 0; j < 8; ++j)
#pragma unroll
            for (int v = 0; v < 4; ++v) {
                int row = rb0 + wv * 16 + q * 4 + v;
                z_out[(size_t)row * 128 + j * 16 + l15] = f2b(sigm(acc[j][v] + bv[j]));
            }
    } else if (mode == 1) {
        float bv[8];
#pragma unroll
        for (int j = 0; j < 8; ++j) bv[j] = br[j * 16 + l15];
#pragma unroll
        for (int j = 0; j < 8; ++j)
#pragma unroll
            for (int v = 0; v < 4; ++v) {
                int row = rb0 + wv * 16 + q * 4 + v;
                float r = sigm(acc[j][v] + bv[j]);
                float hh = h_prev[(size_t)row * 128 + j * 16 + l15];
                rh_out[(size_t)row * 128 + j * 16 + l15] = f2b(r * hh);
            }
    } else {
        float bv[8], gv[8], bev[8];
#pragma unroll
        for (int j = 0; j < 8; ++j) {
            bv[j] = bc[j * 16 + l15];
            gv[j] = gamma[j * 16 + l15];
            bev[j] = beta[j * 16 + l15];
        }
#pragma unroll
        for (int v = 0; v < 4; ++v) {
            const int row = rb0 + wv * 16 + q * 4 + v;
            float hn[8];
            float s = 0.f;
#pragma unroll
            for (int j = 0; j < 8; ++j) {
                float hc = tanh_fast(acc[j][v] + bv[j]);
                float zz = b2f((uint_t)z_in[(size_t)row * 128 + j * 16 + l15]);
                float hh = h_prev[(size_t)row * 128 + j * 16 + l15];
                hn[j] = (1.0f - zz) * hh + zz * hc;
                s += hn[j];
            }
#pragma unroll
            for (int o = 8; o > 0; o >>= 1) s += __shfl_xor(s, o);  // 16-lane quad
            float mu = s * (1.0f / 128.0f);
            float vv = 0.f;
#pragma unroll
            for (int j = 0; j < 8; ++j) {
                float d = hn[j] - mu;
                vv += d * d;
            }
#pragma unroll
            for (int o = 8; o > 0; o >>= 1) vv += __shfl_xor(vv, o);
            float inv = rsqrtf(vv * (1.0f / 128.0f) + LN_EPS);
#pragma unroll
            for (int j = 0; j < 8; ++j)
                f_out[(size_t)row * 128 + j * 16 + l15] =
                    (hn[j] - mu) * inv * gv[j] + bev[j];
        }
    }
}

// ---------------- launch ----------------

extern "C" void kernel_launch(void* const* d_in, const int* in_sizes, int n_in,
                              void* d_out, int out_size, void* d_ws, size_t ws_size,
                              hipStream_t stream) {
    const float* x = (const float*)d_in[0];
    const int* ei = (const int*)d_in[1];
    const float* h = (const float*)d_in[2];
    const float* Wz = (const float*)d_in[3];
    const float* bz = (const float*)d_in[4];
    const float* Wr = (const float*)d_in[5];
    const float* br = (const float*)d_in[6];
    const float* Wc = (const float*)d_in[7];
    const float* bcv = (const float*)d_in[8];
    const float* gamma = (const float*)d_in[9];
    const float* beta = (const float*)d_in[10];
    float* out = (float*)d_out;

    char* w = (char*)d_ws;
    int* offs = (int*)(w + 0);                    //    40,004 B
    float* dis = (float*)(w + 40960);             //    40,000 B
    int* csr_src = (int*)(w + 81920);             //   640,000 B
    ushort_t* csr_w = (ushort_t*)(w + 721920);    //   320,000 B
    ushort_t* Wt_zr = (ushort_t*)(w + 1041920);   //   131,072 B
    ushort_t* Wt_c = (ushort_t*)(w + 1172992);    //    65,536 B
    ushort_t* xb = (ushort_t*)(w + 1239040);      // 20,480,000 B
    ushort_t* hb = (ushort_t*)(w + 21719040);     // 20,480,000 B
    ushort_t* agg_x = (ushort_t*)(w + 42199040);  // 20,480,000 B
    ushort_t* agg_h = (ushort_t*)(w + 62679040);  // 20,480,000 B -> end 83,159,040
    // aliases (strict lifetime reuse on one stream):
    int* cnt = (int*)(w + 1239040);     // dead after fill_csr, before packwt_k
    int* cursor = (int*)(w + 1280000);  // dead after fill_csr
    int* bsum = (int*)(w + 1320000);    // dead after scan3
    ushort_t* z_buf = xb;      // xb dead after gather16<2>; written by gemm<0>
    ushort_t* rh_bf = hb;      // hb dead after gather16<2>; written by gemm<0>
    ushort_t* agg_rh = agg_h;  // agg_h dead after gemm<0>

    hipMemsetAsync(cnt, 0, NN * sizeof(int), stream);
    count_deg<<<EE / 256, 256, 0, stream>>>(ei, cnt);
    scan1<<<40, 256, 0, stream>>>(cnt, offs, bsum);
    scan3<<<40, 256, 0, stream>>>(cnt, bsum, offs, cursor, dis);
    fill_csr<<<EE / 256, 256, 0, stream>>>(ei, cursor, dis, csr_src, csr_w);
    packwt_k<<<10384, 256, 0, stream>>>(x, h, xb, hb, Wz, Wr, Wc, Wt_zr, Wt_c);

    // agg_x, agg_h in one fused pass: 16 nodes per block, batch = blockIdx&7
    gather16<2><<<(NN / 16) * 8, 256, 0, stream>>>(xb, hb, offs, csr_src, csr_w, dis,
                                                   agg_x, agg_h);
    // z (y=0) and rh (y=1) from one GEMM over [agg_x|agg_h]
    gemm_k<0><<<dim3(80000 / 128, 2), 512, 0, stream>>>(
        agg_x, agg_h, Wt_zr, bz, br, bcv, h, (const ushort_t*)0, gamma, beta,
        z_buf, rh_bf, (float*)0);
    gather16<1><<<(NN / 16) * 8, 256, 0, stream>>>(rh_bf, (const ushort_t*)0, offs,
                                                   csr_src, csr_w, dis, agg_rh,
                                                   (ushort_t*)0);
    // out = LN(GRU(tanh([agg_x|agg_rh]@Wc + bc)))
    gemm_k<1><<<dim3(80000 / 128, 1), 512, 0, stream>>>(
        agg_x, agg_rh, Wt_c, bz, br, bcv, h, z_buf, gamma, beta,
        (ushort_t*)0, (ushort_t*)0, out);
}

// Round 6
// 291.734 us; speedup vs baseline: 1.3146x; 1.0370x over previous
//
#include <hip/hip_runtime.h>

#define NN 10000
#define BB 8
#define EE 160000
#define DH 128
#define LN_EPS 1e-5f

typedef unsigned short ushort_t;
typedef unsigned int uint_t;

typedef __bf16 bf16x8 __attribute__((ext_vector_type(8)));
typedef float floatx4 __attribute__((ext_vector_type(4)));
typedef float floatx2 __attribute__((ext_vector_type(2)));

__device__ __forceinline__ float b2f(uint_t u) { return __uint_as_float(u << 16); }
__device__ __forceinline__ ushort_t f2b(float f) {
    uint_t u = __float_as_uint(f);
    return (ushort_t)((u + 0x7fffu + ((u >> 16) & 1u)) >> 16);
}
__device__ __forceinline__ uint_t pack2(float lo, float hi) {
    return (uint_t)f2b(lo) | ((uint_t)f2b(hi) << 16);
}
__device__ __forceinline__ float sigm(float x) { return 1.0f / (1.0f + __expf(-x)); }
__device__ __forceinline__ float tanh_fast(float x) {
    float ex = __expf(2.0f * x);
    return 1.0f - 2.0f / (ex + 1.0f);
}

// unpack u32 holding 2 bf16 -> float2
__device__ __forceinline__ floatx2 unpk(uint_t u) {
    floatx2 r;
    r.x = __uint_as_float(u << 16);
    r.y = __uint_as_float(u & 0xffff0000u);
    return r;
}
// packed dual-FMA: a += w * v  (one VALU inst per 2 floats)
__device__ __forceinline__ void pk_fma(floatx2& a, floatx2 w, floatx2 v) {
    asm("v_pk_fma_f32 %0, %1, %2, %0" : "+v"(a) : "v"(w), "v"(v));
}
// accumulate 8 bf16 (uint4) with packed weight w2: 8 unpack + 4 pk_fma
__device__ __forceinline__ void acc8p(floatx2* a, floatx2 w2, uint4 v) {
    pk_fma(a[0], w2, unpk(v.x));
    pk_fma(a[1], w2, unpk(v.y));
    pk_fma(a[2], w2, unpk(v.z));
    pk_fma(a[3], w2, unpk(v.w));
}

// ---------------- CSR build ----------------

__global__ void count_deg(const int* __restrict__ ei, int* __restrict__ cnt) {
    int e = blockIdx.x * 256 + threadIdx.x;
    if (e < EE) atomicAdd(&cnt[ei[EE + e]], 1);
}

__global__ __launch_bounds__(256) void scan1(const int* __restrict__ cnt,
                                             int* __restrict__ offs,
                                             int* __restrict__ bsum) {
    __shared__ int s[256];
    const int t = threadIdx.x, idx = blockIdx.x * 256 + t;
    int x = (idx < NN) ? cnt[idx] : 0;
    s[t] = x;
    __syncthreads();
    for (int o = 1; o < 256; o <<= 1) {
        int v = s[t];
        int u = (t >= o) ? s[t - o] : 0;
        __syncthreads();
        s[t] = v + u;
        __syncthreads();
    }
    if (idx < NN) offs[idx] = s[t] - x;  // block-local exclusive
    if (t == 255) bsum[blockIdx.x] = s[255];
}

// scan3 also does the cross-block prefix (scan2 fused away)
__global__ __launch_bounds__(256) void scan3(const int* __restrict__ cnt,
                                             const int* __restrict__ bsum,
                                             int* __restrict__ offs,
                                             int* __restrict__ cursor,
                                             float* __restrict__ dis) {
    __shared__ int sb[40];
    __shared__ int pfx;
    const int t = threadIdx.x;
    if (t < 40) sb[t] = bsum[t];
    __syncthreads();
    if (t == 0) {
        int a = 0;
        for (int i = 0; i < blockIdx.x; ++i) a += sb[i];
        pfx = a;
    }
    __syncthreads();
    const int idx = blockIdx.x * 256 + t;
    if (idx < NN) {
        int off = offs[idx] + pfx;
        offs[idx] = off;
        cursor[idx] = off;
        dis[idx] = rsqrtf((float)(cnt[idx] + 1));
    }
    if (idx == 0) offs[NN] = EE;
}

// csr packed: bf16(dis[src])<<16 | src   (src < 16384 fits 14 bits)
__global__ void fill_csr(const int* __restrict__ ei, int* __restrict__ cursor,
                         const float* __restrict__ dis, int* __restrict__ csr_pk) {
    int e = blockIdx.x * 256 + threadIdx.x;
    if (e < EE) {
        int s = ei[e];
        int d = ei[EE + e];
        int pos = atomicAdd(&cursor[d], 1);
        csr_pk[pos] = (int)(((uint_t)f2b(dis[s]) << 16) | (uint_t)s);
    }
}

// ---------------- pack x,h -> bf16 + weight transpose (merged) ----------------

__global__ __launch_bounds__(256) void packwt_k(const float* __restrict__ x,
                                                const float* __restrict__ h,
                                                ushort_t* __restrict__ xb,
                                                ushort_t* __restrict__ hb,
                                                const float* __restrict__ Wz,
                                                const float* __restrict__ Wr,
                                                const float* __restrict__ Wc,
                                                ushort_t* __restrict__ Wt_zr,
                                                ushort_t* __restrict__ Wt_c) {
    if (blockIdx.x < 10000) {
        const size_t o = ((size_t)blockIdx.x * 256 + threadIdx.x) * 4;
        float4 vx = *(const float4*)(x + o);
        uint2 px;
        px.x = pack2(vx.x, vx.y);
        px.y = pack2(vx.z, vx.w);
        *(uint2*)(xb + o) = px;
        float4 vh = *(const float4*)(h + o);
        uint2 ph;
        ph.x = pack2(vh.x, vh.y);
        ph.y = pack2(vh.z, vh.w);
        *(uint2*)(hb + o) = ph;
    } else {
        const int col = blockIdx.x - 10000, k = threadIdx.x;
        if (col < 256) {
            float v = (col < 128) ? Wz[(size_t)k * 128 + col]
                                  : Wr[(size_t)k * 128 + col - 128];
            Wt_zr[(size_t)col * 256 + k] = f2b(v);
        } else {
            int c2 = col - 256;
            Wt_c[(size_t)c2 * 256 + k] = f2b(Wc[(size_t)k * 128 + c2]);
        }
    }
}

// ---------------- gather16: 4 waves x 4 nodes/wave, 16 lanes per node -------------
// dst[b,n] = dis[n] * ( sum_e dis[s]*src[b,s] + dis[n]*src[b,n] )
// One 16-lane group per node: lane il owns cols il*8..il*8+7, accumulates ALL edges
// of its node -> lane-private result, no cross-lane reduce. b = blockIdx&7 keeps
// XCD/L2 batch sharding (FETCH ~104 MB). Packed CSR word (w<<16|src) -> ONE
// bpermute per edge; junk slots broadcast 0 -> weight 0.0 -> no predication needed
// (they harmlessly re-read row 0). Loads for 4 edges are issued BEFORE their FMAs:
// 8 uint4 loads in flight per wave (costs ~45 VGPR, buys 4-8x memory parallelism).

template <int NB>
__global__ __launch_bounds__(256) void gather16(
    const ushort_t* __restrict__ src0, const ushort_t* __restrict__ src1,
    const int* __restrict__ offs, const int* __restrict__ csr_pk,
    const float* __restrict__ dis, ushort_t* __restrict__ dst0,
    ushort_t* __restrict__ dst1) {
    const int tid = threadIdx.x, lane = tid & 63;
    const int b = blockIdx.x & 7;
    const int g = lane >> 4, il = lane & 15;
    const int ng = (blockIdx.x >> 3) * 16 + (tid >> 6) * 4 + g;  // my group's node
    const ushort_t* base0 = src0 + (size_t)b * NN * 128;
    const ushort_t* base1 = (NB == 2) ? (src1 + (size_t)b * NN * 128) : base0;
    const uint_t cofs = (uint_t)il * 8u;

    floatx2 a0[4], a1[4];
#pragma unroll
    for (int j = 0; j < 4; ++j) {
        a0[j] = (floatx2){0.f, 0.f};
        a1[j] = (floatx2){0.f, 0.f};
    }

    const int e0 = offs[ng], e1 = offs[ng + 1];
    const float dn = dis[ng];

    {  // self row, weight dn inside the sum
        const floatx2 d2 = {dn, dn};
        const uint_t off = (uint_t)ng * 128u + cofs;
        acc8p(a0, d2, *(const uint4*)(base0 + off));
        if (NB == 2) acc8p(a1, d2, *(const uint4*)(base1 + off));
    }

    // max degree over the wave's 4 groups -> uniform loop bound
    int mx = e1 - e0;
    mx = max(mx, __shfl_xor(mx, 16));
    mx = max(mx, __shfl_xor(mx, 32));
    const int dmax = __builtin_amdgcn_readfirstlane(mx);
    const int pbase = (lane & 48) << 2;  // bpermute byte base of group's lane 0

    for (int ibase = 0; ibase < dmax; ibase += 16) {
        // refill: lane il of group g holds packed edge e0+ibase+il (0 if past end)
        int pk = 0;
        const int pos = e0 + ibase + il;
        if (pos < e1) pk = csr_pk[pos];
        const int lim = (dmax - ibase) < 16 ? (dmax - ibase) : 16;
        int pidx = pbase;
#pragma unroll 1
        for (int i = 0; i < lim; i += 4) {
            // metadata for 4 edges (junk slots -> pk=0 -> w=0, row 0)
            const int p0 = __builtin_amdgcn_ds_bpermute(pidx, pk);
            const int p1 = __builtin_amdgcn_ds_bpermute(pidx + 4, pk);
            const int p2 = __builtin_amdgcn_ds_bpermute(pidx + 8, pk);
            const int p3 = __builtin_amdgcn_ds_bpermute(pidx + 12, pk);
            pidx += 16;
            const uint_t q0 = (uint_t)(p0 & 0xffff) * 128u + cofs;
            const uint_t q1 = (uint_t)(p1 & 0xffff) * 128u + cofs;
            const uint_t q2 = (uint_t)(p2 & 0xffff) * 128u + cofs;
            const uint_t q3 = (uint_t)(p3 & 0xffff) * 128u + cofs;
            // issue ALL loads before any FMA: 8 in flight (NB=2)
            uint4 v0 = *(const uint4*)(base0 + q0);
            uint4 v1 = *(const uint4*)(base0 + q1);
            uint4 v2 = *(const uint4*)(base0 + q2);
            uint4 v3 = *(const uint4*)(base0 + q3);
            uint4 u0, u1, u2, u3;
            if (NB == 2) {
                u0 = *(const uint4*)(base1 + q0);
                u1 = *(const uint4*)(base1 + q1);
                u2 = *(const uint4*)(base1 + q2);
                u3 = *(const uint4*)(base1 + q3);
            }
            const float f0 = __uint_as_float((uint_t)p0 & 0xffff0000u);
            const float f1 = __uint_as_float((uint_t)p1 & 0xffff0000u);
            const float f2 = __uint_as_float((uint_t)p2 & 0xffff0000u);
            const float f3 = __uint_as_float((uint_t)p3 & 0xffff0000u);
            const floatx2 w0 = {f0, f0}, w1 = {f1, f1}, w2 = {f2, f2}, w3 = {f3, f3};
            acc8p(a0, w0, v0);
            acc8p(a0, w1, v1);
            acc8p(a0, w2, v2);
            acc8p(a0, w3, v3);
            if (NB == 2) {
                acc8p(a1, w0, u0);
                acc8p(a1, w1, u1);
                acc8p(a1, w2, u2);
                acc8p(a1, w3, u3);
            }
        }
    }

    // lane-private result: scale by dn, pack, store (all 64 lanes)
    const size_t o = ((size_t)b * NN + ng) * 128 + cofs;
    uint4 st;
    st.x = pack2(a0[0].x * dn, a0[0].y * dn);
    st.y = pack2(a0[1].x * dn, a0[1].y * dn);
    st.z = pack2(a0[2].x * dn, a0[2].y * dn);
    st.w = pack2(a0[3].x * dn, a0[3].y * dn);
    *(uint4*)(dst0 + o) = st;
    if (NB == 2) {
        uint4 st1;
        st1.x = pack2(a1[0].x * dn, a1[0].y * dn);
        st1.y = pack2(a1[1].x * dn, a1[1].y * dn);
        st1.z = pack2(a1[2].x * dn, a1[2].y * dn);
        st1.w = pack2(a1[3].x * dn, a1[3].y * dn);
        *(uint4*)(dst1 + o) = st1;
    }
}

// ---------------- GEMM 128x128 tile, K=256 = [A1 | A2] @ Wt, fused epilogues ------
// 512 threads / 8 waves: wave w owns rows w*16..w*16+15 (acc = 8 x floatx4).
// Register-prefetch pipeline: k0+1's global loads issued before k0's MFMA compute,
// consumed by ds_write after the next barrier -> HBM latency hidden under compute.
// PHASE 0: mode=blockIdx.y (0: z=sigma->z_buf bf16; 1: r=sigma, rh=r*h->rh bf16)
// PHASE 1: mode 2: tanh, GRU blend, LayerNorm -> out f32

template <int PHASE>
__global__ __launch_bounds__(512) void gemm_k(
    const ushort_t* __restrict__ A1, const ushort_t* __restrict__ A2,
    const ushort_t* __restrict__ Wt, const float* __restrict__ bz,
    const float* __restrict__ br, const float* __restrict__ bc,
    const float* __restrict__ h_prev, const ushort_t* __restrict__ z_in,
    const float* __restrict__ gamma, const float* __restrict__ beta,
    ushort_t* __restrict__ z_out, ushort_t* __restrict__ rh_out,
    float* __restrict__ f_out) {
    __shared__ __align__(16) ushort_t As[128 * 72];
    __shared__ __align__(16) ushort_t Bs[128 * 72];
    const int tid = threadIdx.x;
    const int rb0 = blockIdx.x * 128;
    const int mode = (PHASE == 1) ? 2 : blockIdx.y;
    const int cb0 = (mode == 1) ? 128 : 0;

    const int wv = tid >> 6, lane = tid & 63;
    const int l15 = lane & 15, q = lane >> 4;
    const int sr = tid >> 2;        // 0..127: A row / B col staged by this thread
    const int kh = (tid & 3) * 16;  // 16-element K chunk

    floatx4 acc[8];
#pragma unroll
    for (int j = 0; j < 8; ++j) acc[j] = (floatx4){0.f, 0.f, 0.f, 0.f};

    uint4 pa0, pa1, pb0, pb1;  // prefetch registers (one K-step tile slice)
#define LOAD_AB(k0)                                                                   \
    {                                                                                 \
        const int kg = (k0) + kh;                                                     \
        const ushort_t* sA = (kg < 128)                                               \
                                 ? (A1 + (size_t)(rb0 + sr) * 128 + kg)               \
                                 : (A2 + (size_t)(rb0 + sr) * 128 + (kg - 128));      \
        pa0 = *(const uint4*)(sA);                                                    \
        pa1 = *(const uint4*)(sA + 8);                                                \
        const ushort_t* sB = Wt + (size_t)(cb0 + sr) * 256 + (k0) + kh;               \
        pb0 = *(const uint4*)(sB);                                                    \
        pb1 = *(const uint4*)(sB + 8);                                                \
    }

    LOAD_AB(0);
#pragma unroll
    for (int t = 0; t < 4; ++t) {
        if (t) __syncthreads();  // all waves done reading previous tile
        *(uint4*)(&As[sr * 72 + kh]) = pa0;
        *(uint4*)(&As[sr * 72 + kh + 8]) = pa1;
        *(uint4*)(&Bs[sr * 72 + kh]) = pb0;
        *(uint4*)(&Bs[sr * 72 + kh + 8]) = pb1;
        __syncthreads();
        if (t < 3) LOAD_AB((t + 1) * 64);  // prefetch next tile under compute
#pragma unroll
        for (int ks = 0; ks < 2; ++ks) {
            const int ko = ks * 32 + q * 8;
            bf16x8 a0 = *(const bf16x8*)&As[(wv * 16 + l15) * 72 + ko];
#pragma unroll
            for (int j = 0; j < 8; ++j) {
                bf16x8 b = *(const bf16x8*)&Bs[(j * 16 + l15) * 72 + ko];
                acc[j] = __builtin_amdgcn_mfma_f32_16x16x32_bf16(a0, b, acc[j], 0, 0, 0);
            }
        }
    }
#undef LOAD_AB

    // C/D: col = j*16 + l15, row = rb0 + wv*16 + q*4 + v
    if (mode == 0) {
        float bv[8];
#pragma unroll
        for (int j = 0; j < 8; ++j) bv[j] = bz[j * 16 + l15];
#pragma unroll
        for (int j = 0; j < 8; ++j)
#pragma unroll
            for (int v = 0; v < 4; ++v) {
                int row = rb0 + wv * 16 + q * 4 + v;
                z_out[(size_t)row * 128 + j * 16 + l15] = f2b(sigm(acc[j][v] + bv[j]));
            }
    } else if (mode == 1) {
        float bv[8];
#pragma unroll
        for (int j = 0; j < 8; ++j) bv[j] = br[j * 16 + l15];
#pragma unroll
        for (int j = 0; j < 8; ++j)
#pragma unroll
            for (int v = 0; v < 4; ++v) {
                int row = rb0 + wv * 16 + q * 4 + v;
                float r = sigm(acc[j][v] + bv[j]);
                float hh = h_prev[(size_t)row * 128 + j * 16 + l15];
                rh_out[(size_t)row * 128 + j * 16 + l15] = f2b(r * hh);
            }
    } else {
        float bv[8], gv[8], bev[8];
#pragma unroll
        for (int j = 0; j < 8; ++j) {
            bv[j] = bc[j * 16 + l15];
            gv[j] = gamma[j * 16 + l15];
            bev[j] = beta[j * 16 + l15];
        }
#pragma unroll
        for (int v = 0; v < 4; ++v) {
            const int row = rb0 + wv * 16 + q * 4 + v;
            float hn[8];
            float s = 0.f;
#pragma unroll
            for (int j = 0; j < 8; ++j) {
                float hc = tanh_fast(acc[j][v] + bv[j]);
                float zz = b2f((uint_t)z_in[(size_t)row * 128 + j * 16 + l15]);
                float hh = h_prev[(size_t)row * 128 + j * 16 + l15];
                hn[j] = (1.0f - zz) * hh + zz * hc;
                s += hn[j];
            }
#pragma unroll
            for (int o = 8; o > 0; o >>= 1) s += __shfl_xor(s, o);  // 16-lane quad
            float mu = s * (1.0f / 128.0f);
            float vv = 0.f;
#pragma unroll
            for (int j = 0; j < 8; ++j) {
                float d = hn[j] - mu;
                vv += d * d;
            }
#pragma unroll
            for (int o = 8; o > 0; o >>= 1) vv += __shfl_xor(vv, o);
            float inv = rsqrtf(vv * (1.0f / 128.0f) + LN_EPS);
#pragma unroll
            for (int j = 0; j < 8; ++j)
                f_out[(size_t)row * 128 + j * 16 + l15] =
                    (hn[j] - mu) * inv * gv[j] + bev[j];
        }
    }
}

// ---------------- launch ----------------

extern "C" void kernel_launch(void* const* d_in, const int* in_sizes, int n_in,
                              void* d_out, int out_size, void* d_ws, size_t ws_size,
                              hipStream_t stream) {
    const float* x = (const float*)d_in[0];
    const int* ei = (const int*)d_in[1];
    const float* h = (const float*)d_in[2];
    const float* Wz = (const float*)d_in[3];
    const float* bz = (const float*)d_in[4];
    const float* Wr = (const float*)d_in[5];
    const float* br = (const float*)d_in[6];
    const float* Wc = (const float*)d_in[7];
    const float* bcv = (const float*)d_in[8];
    const float* gamma = (const float*)d_in[9];
    const float* beta = (const float*)d_in[10];
    float* out = (float*)d_out;

    char* w = (char*)d_ws;
    int* offs = (int*)(w + 0);                    //    40,004 B
    float* dis = (float*)(w + 40960);             //    40,000 B
    int* csr_pk = (int*)(w + 81920);              //   640,000 B (w<<16|src packed)
    ushort_t* Wt_zr = (ushort_t*)(w + 1041920);   //   131,072 B
    ushort_t* Wt_c = (ushort_t*)(w + 1172992);    //    65,536 B
    ushort_t* xb = (ushort_t*)(w + 1239040);      // 20,480,000 B
    ushort_t* hb = (ushort_t*)(w + 21719040);     // 20,480,000 B
    ushort_t* agg_x = (ushort_t*)(w + 42199040);  // 20,480,000 B
    ushort_t* agg_h = (ushort_t*)(w + 62679040);  // 20,480,000 B -> end 83,159,040
    // aliases (strict lifetime reuse on one stream):
    int* cnt = (int*)(w + 1239040);     // dead after fill_csr, before packwt_k
    int* cursor = (int*)(w + 1280000);  // dead after fill_csr
    int* bsum = (int*)(w + 1320000);    // dead after scan3
    ushort_t* z_buf = xb;      // xb dead after gather16<2>; written by gemm<0>
    ushort_t* rh_bf = hb;      // hb dead after gather16<2>; written by gemm<0>
    ushort_t* agg_rh = agg_h;  // agg_h dead after gemm<0>

    hipMemsetAsync(cnt, 0, NN * sizeof(int), stream);
    count_deg<<<EE / 256, 256, 0, stream>>>(ei, cnt);
    scan1<<<40, 256, 0, stream>>>(cnt, offs, bsum);
    scan3<<<40, 256, 0, stream>>>(cnt, bsum, offs, cursor, dis);
    fill_csr<<<EE / 256, 256, 0, stream>>>(ei, cursor, dis, csr_pk);
    packwt_k<<<10384, 256, 0, stream>>>(x, h, xb, hb, Wz, Wr, Wc, Wt_zr, Wt_c);

    // agg_x, agg_h in one fused pass: 16 nodes per block, batch = blockIdx&7
    gather16<2><<<(NN / 16) * 8, 256, 0, stream>>>(xb, hb, offs, csr_pk, dis,
                                                   agg_x, agg_h);
    // z (y=0) and rh (y=1) from one GEMM over [agg_x|agg_h]
    gemm_k<0><<<dim3(80000 / 128, 2), 512, 0, stream>>>(
        agg_x, agg_h, Wt_zr, bz, br, bcv, h, (const ushort_t*)0, gamma, beta,
        z_buf, rh_bf, (float*)0);
    gather16<1><<<(NN / 16) * 8, 256, 0, stream>>>(rh_bf, (const ushort_t*)0, offs,
                                                   csr_pk, dis, agg_rh,
                                                   (ushort_t*)0);
    // out = LN(GRU(tanh([agg_x|agg_rh]@Wc + bc)))
    gemm_k<1><<<dim3(80000 / 128, 1), 512, 0, stream>>>(
        agg_x, agg_rh, Wt_c, bz, br, bcv, h, z_buf, gamma, beta,
        (ushort_t*)0, (ushort_t*)0, out);
}